// Round 1
// baseline (10944.566 us; speedup 1.0000x reference)
//
#include <hip/hip_runtime.h>
#include <math.h>

#define NENT 50000
#define NR2 460
#define HD 128
#define TS 8
#define EPC 200000   // edges per step
#define MPC 400000   // r_to_e entries per step
#define RSLOPE 0.22916666666666666f

__device__ __forceinline__ void gAdd(float* p, float v) { unsafeAtomicAdd(p, v); }
__device__ __forceinline__ float sigm(float x) { return 1.0f / (1.0f + expf(-x)); }
__device__ __forceinline__ float rrelu_f(float x) { return x >= 0.0f ? x : RSLOPE * x; }

// ---- histogram count: out[t*stride + idx[i]] += 1 ----
__global__ void k_count(const int* __restrict__ idx, float* __restrict__ out,
                        int n, int per_t, int stride) {
  int i = blockIdx.x * blockDim.x + threadIdx.x;
  int gs = gridDim.x * blockDim.x;
  for (; i < n; i += gs) {
    int t = i / per_t;
    gAdd(&out[(size_t)t * stride + idx[i]], 1.0f);
  }
}

// deg -> 1/deg (0 if 0)
__global__ void k_recip(float* __restrict__ v, int n) {
  int i = blockIdx.x * blockDim.x + threadIdx.x;
  if (i < n) { float x = v[i]; v[i] = x > 0.0f ? 1.0f / x : 0.0f; }
}

// ---- row l2 normalize: out[r] = in[r]/max(||in[r]||,eps) ----
__global__ __launch_bounds__(HD) void k_l2rows(const float* __restrict__ in,
                                               float* __restrict__ out) {
  int r = blockIdx.x, j = threadIdx.x;
  __shared__ float red[HD];
  float v = in[(size_t)r * HD + j];
  red[j] = v * v;
  __syncthreads();
  for (int s = HD / 2; s > 0; s >>= 1) { if (j < s) red[j] += red[j + s]; __syncthreads(); }
  float rn = 1.0f / fmaxf(sqrtf(red[0]), 1e-12f);
  out[(size_t)r * HD + j] = v * rn;
}

// ---- segment sum of h[rte[m]] into sums[rel], LDS-tiled over 32-dim chunks ----
__global__ __launch_bounds__(256) void k_relsum(
    const float* __restrict__ h, const int* __restrict__ rte,
    const int* __restrict__ rseg, float* __restrict__ sums) {
  __shared__ float ls[NR2 * 32];
  int tid = threadIdx.x;
  int tx = tid & 31, ty = tid >> 5;
  int dbase = blockIdx.y * 32;
  for (int i = tid; i < NR2 * 32; i += 256) ls[i] = 0.f;
  __syncthreads();
  int chunk = (MPC + gridDim.x - 1) / gridDim.x;
  int m0 = blockIdx.x * chunk;
  int m1 = min(MPC, m0 + chunk);
  for (int m = m0 + ty; m < m1; m += 8) {
    int rel = rseg[m];
    int idx = rte[m];
    float v = h[(size_t)idx * HD + dbase + tx];
    atomicAdd(&ls[rel * 32 + tx], v);
  }
  __syncthreads();
  for (int i = tid; i < NR2 * 32; i += 256)
    gAdd(&sums[(size_t)(i >> 5) * HD + dbase + (i & 31)], ls[i]);
}

// ---- GRU cell + l2norm for 460 relation rows ----
__global__ __launch_bounds__(HD) void k_gru(
    const float* __restrict__ sums, const float* __restrict__ cnt,
    const float* __restrict__ emb_rel, const float* __restrict__ h0s,
    const float* __restrict__ Wih, const float* __restrict__ Whh,
    const float* __restrict__ bih, const float* __restrict__ bhh,
    float* __restrict__ h0d) {
  int r = blockIdx.x, j = threadIdx.x;
  __shared__ __align__(16) float xr[2 * HD];
  __shared__ __align__(16) float hh[HD];
  __shared__ float red[HD];
  float c = cnt[r];
  float inv = c > 0.0f ? 1.0f / c : 0.0f;
  xr[j] = emb_rel[r * HD + j];
  xr[HD + j] = sums[r * HD + j] * inv;
  float hv0 = h0s[r * HD + j];
  hh[j] = hv0;
  __syncthreads();
  float gr = bih[j], gz = bih[HD + j], gn = bih[2 * HD + j];
  const float4* W4 = (const float4*)Wih;
  int rowA = j * 64, rowB = (j + HD) * 64, rowC = (j + 2 * HD) * 64;  // 256/4 f4 per row
  #pragma unroll 4
  for (int k4 = 0; k4 < 64; ++k4) {
    float4 xa = ((const float4*)xr)[k4];
    float4 w0 = W4[rowA + k4];
    float4 w1 = W4[rowB + k4];
    float4 w2 = W4[rowC + k4];
    gr += w0.x * xa.x + w0.y * xa.y + w0.z * xa.z + w0.w * xa.w;
    gz += w1.x * xa.x + w1.y * xa.y + w1.z * xa.z + w1.w * xa.w;
    gn += w2.x * xa.x + w2.y * xa.y + w2.z * xa.z + w2.w * xa.w;
  }
  float hr = bhh[j], hz = bhh[HD + j], hn = bhh[2 * HD + j];
  const float4* Wh4 = (const float4*)Whh;
  int rA = j * 32, rB = (j + HD) * 32, rC = (j + 2 * HD) * 32;  // 128/4 f4 per row
  #pragma unroll 4
  for (int k4 = 0; k4 < 32; ++k4) {
    float4 xa = ((const float4*)hh)[k4];
    float4 w0 = Wh4[rA + k4];
    float4 w1 = Wh4[rB + k4];
    float4 w2 = Wh4[rC + k4];
    hr += w0.x * xa.x + w0.y * xa.y + w0.z * xa.z + w0.w * xa.w;
    hz += w1.x * xa.x + w1.y * xa.y + w1.z * xa.z + w1.w * xa.w;
    hn += w2.x * xa.x + w2.y * xa.y + w2.z * xa.z + w2.w * xa.w;
  }
  float rg = sigm(gr + hr);
  float zg = sigm(gz + hz);
  float ng = tanhf(gn + rg * hn);
  float hv = (1.0f - zg) * ng + zg * hv0;
  red[j] = hv * hv;
  __syncthreads();
  for (int s = HD / 2; s > 0; s >>= 1) { if (j < s) red[j] += red[j + s]; __syncthreads(); }
  float rn = 1.0f / fmaxf(sqrtf(red[0]), 1e-12f);
  h0d[r * HD + j] = hv * rn;
}

// ---- edge aggregation: agg[dst] += nh[src] + h0[etype]  (pre-matmul, linearity) ----
__global__ __launch_bounds__(256) void k_edge(
    const float* __restrict__ nh, const float* __restrict__ h0,
    const int* __restrict__ src, const int* __restrict__ dst,
    const int* __restrict__ ety, float* __restrict__ agg) {
  int lane = threadIdx.x & 31;
  int g = (blockIdx.x * blockDim.x + threadIdx.x) >> 5;
  int ng = (gridDim.x * blockDim.x) >> 5;
  const float4* nh4 = (const float4*)nh;
  const float4* h04 = (const float4*)h0;
  for (int e = g; e < EPC; e += ng) {
    int s = src[e], d = dst[e], et = ety[e];
    float4 a = nh4[(size_t)s * 32 + lane];
    float4 b = h04[(size_t)et * 32 + lane];
    float* p = agg + (size_t)d * HD + lane * 4;
    gAdd(p + 0, a.x + b.x);
    gAdd(p + 1, a.y + b.y);
    gAdd(p + 2, a.z + b.z);
    gAdd(p + 3, a.w + b.w);
  }
}

// ---- in-place A = rrelu((A * rnorm[:,None]) @ W), A:[nrows][128], W:[128][128] ----
__global__ __launch_bounds__(256) void k_mm_rrelu(
    float* __restrict__ A, const float* __restrict__ W,
    const float* __restrict__ rnorm, int nrows) {
  __shared__ __align__(16) float Ws[HD * HD];
  __shared__ float4 As[64 * 33];
  int tid = threadIdx.x;
  int base = blockIdx.x * 64;
  int rows = min(64, nrows - base);
  float4* Ws4 = (float4*)Ws;
  const float4* Wg4 = (const float4*)W;
  for (int i = tid; i < HD * HD / 4; i += 256) Ws4[i] = Wg4[i];
  const float4* A4 = (const float4*)A;
  for (int i = tid; i < 64 * 32; i += 256) {
    int r = i >> 5, c = i & 31;
    float4 v = make_float4(0.f, 0.f, 0.f, 0.f);
    if (r < rows) {
      v = A4[(size_t)(base + r) * 32 + c];
      float nm = rnorm[base + r];
      v.x *= nm; v.y *= nm; v.z *= nm; v.w *= nm;
    }
    As[r * 33 + c] = v;
  }
  __syncthreads();
  int rg = tid >> 4, cg = tid & 15;
  int r0 = rg * 4, j0c = cg * 2;
  float acc[4][8];
  #pragma unroll
  for (int i = 0; i < 4; ++i)
    #pragma unroll
    for (int c = 0; c < 8; ++c) acc[i][c] = 0.f;
  for (int k4 = 0; k4 < 32; ++k4) {
    float4 a0 = As[(r0 + 0) * 33 + k4];
    float4 a1 = As[(r0 + 1) * 33 + k4];
    float4 a2 = As[(r0 + 2) * 33 + k4];
    float4 a3 = As[(r0 + 3) * 33 + k4];
    const float* pa0 = (const float*)&a0;
    const float* pa1 = (const float*)&a1;
    const float* pa2 = (const float*)&a2;
    const float* pa3 = (const float*)&a3;
    #pragma unroll
    for (int kk = 0; kk < 4; ++kk) {
      int k = k4 * 4 + kk;
      float4 wA = Ws4[k * 32 + j0c];
      float4 wB = Ws4[k * 32 + j0c + 1];
      float av[4] = {pa0[kk], pa1[kk], pa2[kk], pa3[kk]};
      #pragma unroll
      for (int i = 0; i < 4; ++i) {
        acc[i][0] += av[i] * wA.x; acc[i][1] += av[i] * wA.y;
        acc[i][2] += av[i] * wA.z; acc[i][3] += av[i] * wA.w;
        acc[i][4] += av[i] * wB.x; acc[i][5] += av[i] * wB.y;
        acc[i][6] += av[i] * wB.z; acc[i][7] += av[i] * wB.w;
      }
    }
  }
  float4* Aw4 = (float4*)A;
  #pragma unroll
  for (int i = 0; i < 4; ++i) {
    if (r0 + i < rows) {
      float4 o0, o1;
      o0.x = rrelu_f(acc[i][0]); o0.y = rrelu_f(acc[i][1]);
      o0.z = rrelu_f(acc[i][2]); o0.w = rrelu_f(acc[i][3]);
      o1.x = rrelu_f(acc[i][4]); o1.y = rrelu_f(acc[i][5]);
      o1.z = rrelu_f(acc[i][6]); o1.w = rrelu_f(acc[i][7]);
      size_t rb = (size_t)(base + r0 + i) * 32;
      Aw4[rb + j0c] = o0;
      Aw4[rb + j0c + 1] = o1;
    }
  }
}

// ---- fused: cur = l2norm(C); tw = sigmoid(Hin@Wt + b); Hout = tw*cur + (1-tw)*Hin ----
__global__ __launch_bounds__(256) void k_final(
    const float* __restrict__ C, const float* __restrict__ Hin, float* __restrict__ Hout,
    const float* __restrict__ Wt, const float* __restrict__ bias, int nrows) {
  __shared__ __align__(16) float Ws[HD * HD];
  __shared__ float4 Hs[64 * 33];
  __shared__ float4 Cs[64 * 33];
  __shared__ float pr[64][17];
  __shared__ float rn[64];
  __shared__ float bs[HD];
  int tid = threadIdx.x;
  int base = blockIdx.x * 64;
  int rows = min(64, nrows - base);
  float4* Ws4 = (float4*)Ws;
  const float4* Wg4 = (const float4*)Wt;
  for (int i = tid; i < HD * HD / 4; i += 256) Ws4[i] = Wg4[i];
  if (tid < HD) bs[tid] = bias[tid];
  const float4* H4 = (const float4*)Hin;
  const float4* C4 = (const float4*)C;
  for (int i = tid; i < 64 * 32; i += 256) {
    int r = i >> 5, c = i & 31;
    float4 h = make_float4(0.f, 0.f, 0.f, 0.f);
    float4 cc = make_float4(0.f, 0.f, 0.f, 0.f);
    if (r < rows) {
      h = H4[(size_t)(base + r) * 32 + c];
      cc = C4[(size_t)(base + r) * 32 + c];
    }
    Hs[r * 33 + c] = h;
    Cs[r * 33 + c] = cc;
  }
  __syncthreads();
  int rg = tid >> 4, cg = tid & 15;
  int r0 = rg * 4, j0 = cg * 8, j0c = cg * 2;
  const float* Cf = (const float*)Cs;
  const float* Hf = (const float*)Hs;
  #pragma unroll
  for (int i = 0; i < 4; ++i) {
    float s = 0.f;
    #pragma unroll
    for (int c = 0; c < 8; ++c) { float x = Cf[(r0 + i) * 132 + j0 + c]; s += x * x; }
    pr[r0 + i][cg] = s;
  }
  __syncthreads();
  if (tid < 64) {
    float s = 0.f;
    #pragma unroll
    for (int c = 0; c < 16; ++c) s += pr[tid][c];
    rn[tid] = 1.0f / fmaxf(sqrtf(s), 1e-12f);
  }
  __syncthreads();
  float acc[4][8];
  #pragma unroll
  for (int i = 0; i < 4; ++i)
    #pragma unroll
    for (int c = 0; c < 8; ++c) acc[i][c] = 0.f;
  for (int k4 = 0; k4 < 32; ++k4) {
    float4 a0 = Hs[(r0 + 0) * 33 + k4];
    float4 a1 = Hs[(r0 + 1) * 33 + k4];
    float4 a2 = Hs[(r0 + 2) * 33 + k4];
    float4 a3 = Hs[(r0 + 3) * 33 + k4];
    const float* pa0 = (const float*)&a0;
    const float* pa1 = (const float*)&a1;
    const float* pa2 = (const float*)&a2;
    const float* pa3 = (const float*)&a3;
    #pragma unroll
    for (int kk = 0; kk < 4; ++kk) {
      int k = k4 * 4 + kk;
      float4 wA = Ws4[k * 32 + j0c];
      float4 wB = Ws4[k * 32 + j0c + 1];
      float av[4] = {pa0[kk], pa1[kk], pa2[kk], pa3[kk]};
      #pragma unroll
      for (int i = 0; i < 4; ++i) {
        acc[i][0] += av[i] * wA.x; acc[i][1] += av[i] * wA.y;
        acc[i][2] += av[i] * wA.z; acc[i][3] += av[i] * wA.w;
        acc[i][4] += av[i] * wB.x; acc[i][5] += av[i] * wB.y;
        acc[i][6] += av[i] * wB.z; acc[i][7] += av[i] * wB.w;
      }
    }
  }
  float4* O4 = (float4*)Hout;
  #pragma unroll
  for (int i = 0; i < 4; ++i) {
    if (r0 + i < rows) {
      int r = r0 + i;
      float rnv = rn[r];
      float o[8];
      #pragma unroll
      for (int c = 0; c < 8; ++c) {
        float tw = sigm(acc[i][c] + bs[j0 + c]);
        float hval = Hf[r * 132 + j0 + c];
        float chv = Cf[r * 132 + j0 + c] * rnv;
        o[c] = tw * chv + (1.0f - tw) * hval;
      }
      size_t rb = (size_t)(base + r) * 32;
      O4[rb + j0c] = make_float4(o[0], o[1], o[2], o[3]);
      O4[rb + j0c + 1] = make_float4(o[4], o[5], o[6], o[7]);
    }
  }
}

extern "C" void kernel_launch(void* const* d_in, const int* in_sizes, int n_in,
                              void* d_out, int out_size, void* d_ws, size_t ws_size,
                              hipStream_t stream) {
  const int* src    = (const int*)d_in[0];
  const int* dst    = (const int*)d_in[1];
  const int* etype  = (const int*)d_in[2];
  const int* rte    = (const int*)d_in[3];
  const int* rseg   = (const int*)d_in[4];
  const float* dyn  = (const float*)d_in[5];
  const float* emb_rel = (const float*)d_in[6];
  const float* W_ih = (const float*)d_in[7];
  const float* W_hh = (const float*)d_in[8];
  const float* b_ih = (const float*)d_in[9];
  const float* b_hh = (const float*)d_in[10];
  const float* rgcnW = (const float*)d_in[11];
  const float* tgW  = (const float*)d_in[12];
  const float* tgB  = (const float*)d_in[13];
  float* out = (float*)d_out;

  float* ws = (float*)d_ws;
  size_t off = 0;
  float* agg1 = ws + off; off += (size_t)NENT * HD;
  float* agg2 = ws + off; off += (size_t)NENT * HD;
  float* sums = ws + off; off += (size_t)NR2 * HD;
  float* h0a  = ws + off; off += (size_t)NR2 * HD;
  float* h0b  = ws + off; off += (size_t)NR2 * HD;
  float* cnt  = ws + off; off += (size_t)TS * NR2;
  float* normv = ws + off; off += (size_t)TS * NENT;
  (void)ws_size; (void)in_sizes; (void)n_in; (void)out_size;

  // hoisted: per-step relation counts and 1/deg norms (input-only)
  hipMemsetAsync(cnt, 0, (size_t)TS * NR2 * sizeof(float), stream);
  hipMemsetAsync(normv, 0, (size_t)TS * NENT * sizeof(float), stream);
  k_count<<<1024, 256, 0, stream>>>(rseg, cnt, TS * MPC, MPC, NR2);
  k_count<<<1024, 256, 0, stream>>>(dst, normv, TS * EPC, EPC, NENT);
  k_recip<<<(TS * NENT + 255) / 256, 256, 0, stream>>>(normv, TS * NENT);
  // h_init = l2norm(dynamic_emb) -> lives in d_out slot 0 (step 0 is row-wise in-place)
  k_l2rows<<<NENT, HD, 0, stream>>>(dyn, out);

  float* h0bufs[2] = {h0a, h0b};
  for (int t = 0; t < TS; ++t) {
    const float* h = out + (size_t)(t == 0 ? 0 : (t - 1)) * NENT * HD;
    float* hout = out + (size_t)t * NENT * HD;
    const float* h0s = (t == 0) ? emb_rel : h0bufs[(t - 1) & 1];
    float* h0d = h0bufs[t & 1];
    const int* src_t = src + (size_t)t * EPC;
    const int* dst_t = dst + (size_t)t * EPC;
    const int* ety_t = etype + (size_t)t * EPC;
    const int* rte_t = rte + (size_t)t * MPC;
    const int* rsg_t = rseg + (size_t)t * MPC;
    const float* norm_t = normv + (size_t)t * NENT;
    const float* cnt_t = cnt + (size_t)t * NR2;

    hipMemsetAsync(sums, 0, (size_t)NR2 * HD * sizeof(float), stream);
    k_relsum<<<dim3(64, 4), 256, 0, stream>>>(h, rte_t, rsg_t, sums);
    k_gru<<<NR2, HD, 0, stream>>>(sums, cnt_t, emb_rel, h0s, W_ih, W_hh, b_ih, b_hh, h0d);

    hipMemsetAsync(agg1, 0, (size_t)NENT * HD * sizeof(float), stream);
    k_edge<<<2048, 256, 0, stream>>>(h, h0d, src_t, dst_t, ety_t, agg1);
    k_mm_rrelu<<<(NENT + 63) / 64, 256, 0, stream>>>(agg1, rgcnW, norm_t, NENT);

    hipMemsetAsync(agg2, 0, (size_t)NENT * HD * sizeof(float), stream);
    k_edge<<<2048, 256, 0, stream>>>(agg1, h0d, src_t, dst_t, ety_t, agg2);
    k_mm_rrelu<<<(NENT + 63) / 64, 256, 0, stream>>>(agg2, rgcnW + HD * HD, norm_t, NENT);

    k_final<<<(NENT + 63) / 64, 256, 0, stream>>>(agg2, h, hout, tgW, tgB, NENT);
  }
  hipMemcpyAsync(out + (size_t)TS * NENT * HD, h0bufs[(TS - 1) & 1],
                 (size_t)NR2 * HD * sizeof(float), hipMemcpyDeviceToDevice, stream);
}

// Round 2
// 4806.839 us; speedup vs baseline: 2.2769x; 2.2769x over previous
//
#include <hip/hip_runtime.h>
#include <math.h>

#define NENT 50000
#define NR2 460
#define HD 128
#define TS 8
#define EPC 200000   // edges per step
#define MPC 400000   // r_to_e entries per step
#define RSLOPE 0.22916666666666666f
#define NB_E ((NENT + 255) / 256)   // 196 scan blocks

__device__ __forceinline__ float sigm(float x) { return 1.0f / (1.0f + expf(-x)); }
__device__ __forceinline__ float rrelu_f(float x) { return x >= 0.0f ? x : RSLOPE * x; }

// ---- row l2 normalize ----
__global__ __launch_bounds__(HD) void k_l2rows(const float* __restrict__ in,
                                               float* __restrict__ out) {
  int r = blockIdx.x, j = threadIdx.x;
  __shared__ float red[HD];
  float v = in[(size_t)r * HD + j];
  red[j] = v * v;
  __syncthreads();
  for (int s = HD / 2; s > 0; s >>= 1) { if (j < s) red[j] += red[j + s]; __syncthreads(); }
  float rn = 1.0f / fmaxf(sqrtf(red[0]), 1e-12f);
  out[(size_t)r * HD + j] = v * rn;
}

// ---- int histogram ----
__global__ void k_hist(const int* __restrict__ idx, int* __restrict__ cnt, int n) {
  int i = blockIdx.x * blockDim.x + threadIdx.x;
  int gs = gridDim.x * blockDim.x;
  for (; i < n; i += gs) atomicAdd(&cnt[idx[i]], 1);
}

// ---- 3-phase exclusive scan over NENT degrees; also emits 1/deg and cursor copy ----
__global__ __launch_bounds__(256) void k_scan1(const int* __restrict__ deg,
    int* __restrict__ offs, float* __restrict__ normv, int* __restrict__ bsum) {
  __shared__ int sd[256];
  int b = blockIdx.x, tid = threadIdx.x;
  int i = b * 256 + tid;
  int v = (i < NENT) ? deg[i] : 0;
  sd[tid] = v;
  __syncthreads();
  for (int o = 1; o < 256; o <<= 1) {
    int x = (tid >= o) ? sd[tid - o] : 0;
    __syncthreads();
    sd[tid] += x;
    __syncthreads();
  }
  if (i < NENT) {
    offs[i] = sd[tid] - v;                 // exclusive
    normv[i] = v > 0 ? 1.0f / (float)v : 0.0f;
  }
  if (tid == 255) bsum[b] = sd[255];
}

__global__ void k_scan2(int* __restrict__ bsum, int nb) {
  __shared__ int s[512];
  int tid = threadIdx.x;
  for (int i = tid; i < nb; i += blockDim.x) s[i] = bsum[i];
  __syncthreads();
  if (tid == 0) {
    int acc = 0;
    for (int i = 0; i < nb; ++i) { int t = s[i]; s[i] = acc; acc += t; }
  }
  __syncthreads();
  for (int i = tid; i < nb; i += blockDim.x) bsum[i] = s[i];
}

__global__ __launch_bounds__(256) void k_scan3(int* __restrict__ offs, int* __restrict__ cur,
                                               const int* __restrict__ bsum) {
  int b = blockIdx.x;
  int i = b * 256 + threadIdx.x;
  if (i < NENT) {
    int o = offs[i] + bsum[b];
    offs[i] = o;
    cur[i] = o;
  }
  if (b == 0 && threadIdx.x == 0) offs[NENT] = EPC;
}

// ---- tiny scan for 460 relation counts; emits offs, cursor, 1/cnt ----
__global__ void k_scan_rel(const int* __restrict__ cnt, int* __restrict__ offs,
                           int* __restrict__ cur, float* __restrict__ invc) {
  __shared__ int s[NR2 + 1];
  int tid = threadIdx.x;
  for (int i = tid; i < NR2; i += blockDim.x) s[i] = cnt[i];
  __syncthreads();
  if (tid == 0) {
    int acc = 0;
    for (int i = 0; i < NR2; ++i) { int t = s[i]; s[i] = acc; acc += t; }
    s[NR2] = acc;
  }
  __syncthreads();
  for (int i = tid; i <= NR2; i += blockDim.x) offs[i] = s[i];
  for (int i = tid; i < NR2; i += blockDim.x) {
    cur[i] = s[i];
    int c = cnt[i];
    invc[i] = c > 0 ? 1.0f / (float)c : 0.0f;
  }
}

// ---- CSR scatters (input-only, rebuilt every call -> deterministic work) ----
__global__ void k_scatterE(const int* __restrict__ src, const int* __restrict__ dst,
                           const int* __restrict__ ety, int* __restrict__ cur,
                           int2* __restrict__ se) {
  int i = blockIdx.x * blockDim.x + threadIdx.x;
  int gs = gridDim.x * blockDim.x;
  for (; i < EPC; i += gs) {
    int d = dst[i];
    int p = atomicAdd(&cur[d], 1);
    se[p] = make_int2(src[i], ety[i]);
  }
}

__global__ void k_scatterR(const int* __restrict__ rte, const int* __restrict__ rseg,
                           int* __restrict__ cur, int* __restrict__ out) {
  int i = blockIdx.x * blockDim.x + threadIdx.x;
  int gs = gridDim.x * blockDim.x;
  for (; i < MPC; i += gs) {
    int r = rseg[i];
    int p = atomicAdd(&cur[r], 1);
    out[p] = rte[i];
  }
}

// ---- relation partial sums via CSR gather: partials[split][rel][HD] ----
__global__ __launch_bounds__(256) void k_relmean(const float* __restrict__ h,
    const int* __restrict__ offs, const int* __restrict__ rte_csr,
    float* __restrict__ partials) {
  int rel = blockIdx.x, sp = blockIdx.y;
  int o0 = offs[rel], o1 = offs[rel + 1];
  int n = o1 - o0;
  int s0 = o0 + ((n * sp) >> 2);
  int s1 = o0 + ((n * (sp + 1)) >> 2);
  int w = threadIdx.x >> 6, lane = threadIdx.x & 63;
  const float2* h2 = (const float2*)h;
  float sx = 0.f, sy = 0.f;
  int p = s0 + w;
  for (; p + 4 < s1; p += 8) {   // 2-deep ILP, wave-stride 4
    int i0 = rte_csr[p];
    int i1 = rte_csr[p + 4];
    float2 v0 = h2[(size_t)i0 * 64 + lane];
    float2 v1 = h2[(size_t)i1 * 64 + lane];
    sx += v0.x + v1.x; sy += v0.y + v1.y;
  }
  for (; p < s1; p += 4) {
    int i0 = rte_csr[p];
    float2 v0 = h2[(size_t)i0 * 64 + lane];
    sx += v0.x; sy += v0.y;
  }
  __shared__ float red[4][HD];
  red[w][lane * 2] = sx;
  red[w][lane * 2 + 1] = sy;
  __syncthreads();
  if (threadIdx.x < HD) {
    int j = threadIdx.x;
    float t = red[0][j] + red[1][j] + red[2][j] + red[3][j];
    partials[((size_t)sp * NR2 + rel) * HD + j] = t;
  }
}

// ---- GRU cell + l2norm for 460 relation rows ----
__global__ __launch_bounds__(HD) void k_gru(
    const float* __restrict__ partials, const float* __restrict__ invcnt,
    const float* __restrict__ emb_rel, const float* __restrict__ h0s,
    const float* __restrict__ Wih, const float* __restrict__ Whh,
    const float* __restrict__ bih, const float* __restrict__ bhh,
    float* __restrict__ h0d) {
  int r = blockIdx.x, j = threadIdx.x;
  __shared__ __align__(16) float xr[2 * HD];
  __shared__ __align__(16) float hh[HD];
  __shared__ float red[HD];
  float inv = invcnt[r];
  xr[j] = emb_rel[r * HD + j];
  float xm = partials[(0 * NR2 + r) * HD + j] + partials[(1 * NR2 + r) * HD + j] +
             partials[(2 * NR2 + r) * HD + j] + partials[(3 * NR2 + r) * HD + j];
  xr[HD + j] = xm * inv;
  float hv0 = h0s[r * HD + j];
  hh[j] = hv0;
  __syncthreads();
  float gr = bih[j], gz = bih[HD + j], gn = bih[2 * HD + j];
  const float4* W4 = (const float4*)Wih;
  int rowA = j * 64, rowB = (j + HD) * 64, rowC = (j + 2 * HD) * 64;
  #pragma unroll 4
  for (int k4 = 0; k4 < 64; ++k4) {
    float4 xa = ((const float4*)xr)[k4];
    float4 w0 = W4[rowA + k4];
    float4 w1 = W4[rowB + k4];
    float4 w2 = W4[rowC + k4];
    gr += w0.x * xa.x + w0.y * xa.y + w0.z * xa.z + w0.w * xa.w;
    gz += w1.x * xa.x + w1.y * xa.y + w1.z * xa.z + w1.w * xa.w;
    gn += w2.x * xa.x + w2.y * xa.y + w2.z * xa.z + w2.w * xa.w;
  }
  float hr = bhh[j], hz = bhh[HD + j], hn = bhh[2 * HD + j];
  const float4* Wh4 = (const float4*)Whh;
  int rA = j * 32, rB = (j + HD) * 32, rC = (j + 2 * HD) * 32;
  #pragma unroll 4
  for (int k4 = 0; k4 < 32; ++k4) {
    float4 xa = ((const float4*)hh)[k4];
    float4 w0 = Wh4[rA + k4];
    float4 w1 = Wh4[rB + k4];
    float4 w2 = Wh4[rC + k4];
    hr += w0.x * xa.x + w0.y * xa.y + w0.z * xa.z + w0.w * xa.w;
    hz += w1.x * xa.x + w1.y * xa.y + w1.z * xa.z + w1.w * xa.w;
    hn += w2.x * xa.x + w2.y * xa.y + w2.z * xa.z + w2.w * xa.w;
  }
  float rg = sigm(gr + hr);
  float zg = sigm(gz + hz);
  float ng = tanhf(gn + rg * hn);
  float hv = (1.0f - zg) * ng + zg * hv0;
  red[j] = hv * hv;
  __syncthreads();
  for (int s = HD / 2; s > 0; s >>= 1) { if (j < s) red[j] += red[j + s]; __syncthreads(); }
  float rn = 1.0f / fmaxf(sqrtf(red[0]), 1e-12f);
  h0d[r * HD + j] = hv * rn;
}

// ---- edge aggregation via dst-CSR: one wave per dst row, register accumulate ----
__global__ __launch_bounds__(256) void k_edge_csr(
    const float* __restrict__ nh, const float* __restrict__ h0,
    const int* __restrict__ offs, const int2* __restrict__ se,
    const float* __restrict__ norm, float* __restrict__ agg) {
  int gw = (blockIdx.x * blockDim.x + threadIdx.x) >> 6;
  int lane = threadIdx.x & 63;
  if (gw >= NENT) return;
  int o0 = offs[gw], o1 = offs[gw + 1];
  const float2* nh2 = (const float2*)nh;
  const float2* h02 = (const float2*)h0;
  float sx = 0.f, sy = 0.f;
  int p = o0;
  for (; p + 2 <= o1; p += 2) {   // 2-deep ILP
    int2 a = se[p];
    int2 b = se[p + 1];
    float2 va = nh2[(size_t)a.x * 64 + lane];
    float2 ra = h02[(size_t)a.y * 64 + lane];
    float2 vb = nh2[(size_t)b.x * 64 + lane];
    float2 rb = h02[(size_t)b.y * 64 + lane];
    sx += (va.x + ra.x) + (vb.x + rb.x);
    sy += (va.y + ra.y) + (vb.y + rb.y);
  }
  if (p < o1) {
    int2 a = se[p];
    float2 va = nh2[(size_t)a.x * 64 + lane];
    float2 ra = h02[(size_t)a.y * 64 + lane];
    sx += va.x + ra.x;
    sy += va.y + ra.y;
  }
  float nm = norm[gw];
  ((float2*)agg)[(size_t)gw * 64 + lane] = make_float2(sx * nm, sy * nm);
}

// ---- in-place A = rrelu(A @ W), A:[nrows][128], W:[128][128] ----
__global__ __launch_bounds__(256) void k_mm_rrelu(
    float* __restrict__ A, const float* __restrict__ W, int nrows) {
  __shared__ __align__(16) float Ws[HD * HD];
  __shared__ float4 As[64 * 33];
  int tid = threadIdx.x;
  int base = blockIdx.x * 64;
  int rows = min(64, nrows - base);
  float4* Ws4 = (float4*)Ws;
  const float4* Wg4 = (const float4*)W;
  for (int i = tid; i < HD * HD / 4; i += 256) Ws4[i] = Wg4[i];
  const float4* A4 = (const float4*)A;
  for (int i = tid; i < 64 * 32; i += 256) {
    int r = i >> 5, c = i & 31;
    float4 v = make_float4(0.f, 0.f, 0.f, 0.f);
    if (r < rows) v = A4[(size_t)(base + r) * 32 + c];
    As[r * 33 + c] = v;
  }
  __syncthreads();
  int rg = tid >> 4, cg = tid & 15;
  int r0 = rg * 4, j0c = cg * 2;
  float acc[4][8];
  #pragma unroll
  for (int i = 0; i < 4; ++i)
    #pragma unroll
    for (int c = 0; c < 8; ++c) acc[i][c] = 0.f;
  for (int k4 = 0; k4 < 32; ++k4) {
    float4 a0 = As[(r0 + 0) * 33 + k4];
    float4 a1 = As[(r0 + 1) * 33 + k4];
    float4 a2 = As[(r0 + 2) * 33 + k4];
    float4 a3 = As[(r0 + 3) * 33 + k4];
    const float* pa0 = (const float*)&a0;
    const float* pa1 = (const float*)&a1;
    const float* pa2 = (const float*)&a2;
    const float* pa3 = (const float*)&a3;
    #pragma unroll
    for (int kk = 0; kk < 4; ++kk) {
      int k = k4 * 4 + kk;
      float4 wA = Ws4[k * 32 + j0c];
      float4 wB = Ws4[k * 32 + j0c + 1];
      float av[4] = {pa0[kk], pa1[kk], pa2[kk], pa3[kk]};
      #pragma unroll
      for (int i = 0; i < 4; ++i) {
        acc[i][0] += av[i] * wA.x; acc[i][1] += av[i] * wA.y;
        acc[i][2] += av[i] * wA.z; acc[i][3] += av[i] * wA.w;
        acc[i][4] += av[i] * wB.x; acc[i][5] += av[i] * wB.y;
        acc[i][6] += av[i] * wB.z; acc[i][7] += av[i] * wB.w;
      }
    }
  }
  float4* Aw4 = (float4*)A;
  #pragma unroll
  for (int i = 0; i < 4; ++i) {
    if (r0 + i < rows) {
      float4 o0, o1;
      o0.x = rrelu_f(acc[i][0]); o0.y = rrelu_f(acc[i][1]);
      o0.z = rrelu_f(acc[i][2]); o0.w = rrelu_f(acc[i][3]);
      o1.x = rrelu_f(acc[i][4]); o1.y = rrelu_f(acc[i][5]);
      o1.z = rrelu_f(acc[i][6]); o1.w = rrelu_f(acc[i][7]);
      size_t rb = (size_t)(base + r0 + i) * 32;
      Aw4[rb + j0c] = o0;
      Aw4[rb + j0c + 1] = o1;
    }
  }
}

// ---- fused: cur = l2norm(C); tw = sigmoid(Hin@Wt + b); Hout = tw*cur + (1-tw)*Hin ----
__global__ __launch_bounds__(256) void k_final(
    const float* __restrict__ C, const float* __restrict__ Hin, float* __restrict__ Hout,
    const float* __restrict__ Wt, const float* __restrict__ bias, int nrows) {
  __shared__ __align__(16) float Ws[HD * HD];
  __shared__ float4 Hs[64 * 33];
  __shared__ float4 Cs[64 * 33];
  __shared__ float pr[64][17];
  __shared__ float rn[64];
  __shared__ float bs[HD];
  int tid = threadIdx.x;
  int base = blockIdx.x * 64;
  int rows = min(64, nrows - base);
  float4* Ws4 = (float4*)Ws;
  const float4* Wg4 = (const float4*)Wt;
  for (int i = tid; i < HD * HD / 4; i += 256) Ws4[i] = Wg4[i];
  if (tid < HD) bs[tid] = bias[tid];
  const float4* H4 = (const float4*)Hin;
  const float4* C4 = (const float4*)C;
  for (int i = tid; i < 64 * 32; i += 256) {
    int r = i >> 5, c = i & 31;
    float4 h = make_float4(0.f, 0.f, 0.f, 0.f);
    float4 cc = make_float4(0.f, 0.f, 0.f, 0.f);
    if (r < rows) {
      h = H4[(size_t)(base + r) * 32 + c];
      cc = C4[(size_t)(base + r) * 32 + c];
    }
    Hs[r * 33 + c] = h;
    Cs[r * 33 + c] = cc;
  }
  __syncthreads();
  int rg = tid >> 4, cg = tid & 15;
  int r0 = rg * 4, j0 = cg * 8, j0c = cg * 2;
  const float* Cf = (const float*)Cs;
  const float* Hf = (const float*)Hs;
  #pragma unroll
  for (int i = 0; i < 4; ++i) {
    float s = 0.f;
    #pragma unroll
    for (int c = 0; c < 8; ++c) { float x = Cf[(r0 + i) * 132 + j0 + c]; s += x * x; }
    pr[r0 + i][cg] = s;
  }
  __syncthreads();
  if (tid < 64) {
    float s = 0.f;
    #pragma unroll
    for (int c = 0; c < 16; ++c) s += pr[tid][c];
    rn[tid] = 1.0f / fmaxf(sqrtf(s), 1e-12f);
  }
  __syncthreads();
  float acc[4][8];
  #pragma unroll
  for (int i = 0; i < 4; ++i)
    #pragma unroll
    for (int c = 0; c < 8; ++c) acc[i][c] = 0.f;
  for (int k4 = 0; k4 < 32; ++k4) {
    float4 a0 = Hs[(r0 + 0) * 33 + k4];
    float4 a1 = Hs[(r0 + 1) * 33 + k4];
    float4 a2 = Hs[(r0 + 2) * 33 + k4];
    float4 a3 = Hs[(r0 + 3) * 33 + k4];
    const float* pa0 = (const float*)&a0;
    const float* pa1 = (const float*)&a1;
    const float* pa2 = (const float*)&a2;
    const float* pa3 = (const float*)&a3;
    #pragma unroll
    for (int kk = 0; kk < 4; ++kk) {
      int k = k4 * 4 + kk;
      float4 wA = Ws4[k * 32 + j0c];
      float4 wB = Ws4[k * 32 + j0c + 1];
      float av[4] = {pa0[kk], pa1[kk], pa2[kk], pa3[kk]};
      #pragma unroll
      for (int i = 0; i < 4; ++i) {
        acc[i][0] += av[i] * wA.x; acc[i][1] += av[i] * wA.y;
        acc[i][2] += av[i] * wA.z; acc[i][3] += av[i] * wA.w;
        acc[i][4] += av[i] * wB.x; acc[i][5] += av[i] * wB.y;
        acc[i][6] += av[i] * wB.z; acc[i][7] += av[i] * wB.w;
      }
    }
  }
  float4* O4 = (float4*)Hout;
  #pragma unroll
  for (int i = 0; i < 4; ++i) {
    if (r0 + i < rows) {
      int r = r0 + i;
      float rnv = rn[r];
      float o[8];
      #pragma unroll
      for (int c = 0; c < 8; ++c) {
        float tw = sigm(acc[i][c] + bs[j0 + c]);
        float hval = Hf[r * 132 + j0 + c];
        float chv = Cf[r * 132 + j0 + c] * rnv;
        o[c] = tw * chv + (1.0f - tw) * hval;
      }
      size_t rb = (size_t)(base + r) * 32;
      O4[rb + j0c] = make_float4(o[0], o[1], o[2], o[3]);
      O4[rb + j0c + 1] = make_float4(o[4], o[5], o[6], o[7]);
    }
  }
}

extern "C" void kernel_launch(void* const* d_in, const int* in_sizes, int n_in,
                              void* d_out, int out_size, void* d_ws, size_t ws_size,
                              hipStream_t stream) {
  const int* src    = (const int*)d_in[0];
  const int* dst    = (const int*)d_in[1];
  const int* etype  = (const int*)d_in[2];
  const int* rte    = (const int*)d_in[3];
  const int* rseg   = (const int*)d_in[4];
  const float* dyn  = (const float*)d_in[5];
  const float* emb_rel = (const float*)d_in[6];
  const float* W_ih = (const float*)d_in[7];
  const float* W_hh = (const float*)d_in[8];
  const float* b_ih = (const float*)d_in[9];
  const float* b_hh = (const float*)d_in[10];
  const float* rgcnW = (const float*)d_in[11];
  const float* tgW  = (const float*)d_in[12];
  const float* tgB  = (const float*)d_in[13];
  float* out = (float*)d_out;
  (void)in_sizes; (void)n_in; (void)out_size; (void)ws_size;

  float* ws = (float*)d_ws;
  size_t off = 0;
  float* agg1   = ws + off; off += (size_t)NENT * HD;
  float* agg2   = ws + off; off += (size_t)NENT * HD;
  float* parts  = ws + off; off += (size_t)4 * NR2 * HD;
  float* h0a    = ws + off; off += (size_t)NR2 * HD;
  float* h0b    = ws + off; off += (size_t)NR2 * HD;
  float* normv  = ws + off; off += NENT;
  float* invcnt = ws + off; off += NR2;
  // int region (8B-aligned: all prior counts are even)
  int2* csr_se  = (int2*)(ws + off); off += (size_t)2 * EPC;
  int* csr_rte  = (int*)(ws + off);  off += MPC;
  int* degE     = (int*)(ws + off);  off += NENT;
  int* offsE    = (int*)(ws + off);  off += NENT + 2;
  int* curE     = (int*)(ws + off);  off += NENT;
  int* bsum     = (int*)(ws + off);  off += NB_E;
  int* cntR     = (int*)(ws + off);  off += NR2;
  int* offsR    = (int*)(ws + off);  off += NR2 + 2;
  int* curR     = (int*)(ws + off);  off += NR2;

  // h_init = l2norm(dynamic_emb) -> d_out slot 0 doubles as first h
  k_l2rows<<<NENT, HD, 0, stream>>>(dyn, out);

  float* h0bufs[2] = {h0a, h0b};
  for (int t = 0; t < TS; ++t) {
    const float* h = out + (size_t)(t == 0 ? 0 : (t - 1)) * NENT * HD;
    float* hout = out + (size_t)t * NENT * HD;
    const float* h0s = (t == 0) ? emb_rel : h0bufs[(t - 1) & 1];
    float* h0d = h0bufs[t & 1];
    const int* src_t = src + (size_t)t * EPC;
    const int* dst_t = dst + (size_t)t * EPC;
    const int* ety_t = etype + (size_t)t * EPC;
    const int* rte_t = rte + (size_t)t * MPC;
    const int* rsg_t = rseg + (size_t)t * MPC;

    // --- relation CSR build + partial sums + GRU ---
    hipMemsetAsync(cntR, 0, NR2 * sizeof(int), stream);
    k_hist<<<512, 256, 0, stream>>>(rsg_t, cntR, MPC);
    k_scan_rel<<<1, 256, 0, stream>>>(cntR, offsR, curR, invcnt);
    k_scatterR<<<512, 256, 0, stream>>>(rte_t, rsg_t, curR, csr_rte);
    k_relmean<<<dim3(NR2, 4), 256, 0, stream>>>(h, offsR, csr_rte, parts);
    k_gru<<<NR2, HD, 0, stream>>>(parts, invcnt, emb_rel, h0s, W_ih, W_hh, b_ih, b_hh, h0d);

    // --- edge CSR build ---
    hipMemsetAsync(degE, 0, NENT * sizeof(int), stream);
    k_hist<<<256, 256, 0, stream>>>(dst_t, degE, EPC);
    k_scan1<<<NB_E, 256, 0, stream>>>(degE, offsE, normv, bsum);
    k_scan2<<<1, 256, 0, stream>>>(bsum, NB_E);
    k_scan3<<<NB_E, 256, 0, stream>>>(offsE, curE, bsum);
    k_scatterE<<<256, 256, 0, stream>>>(src_t, dst_t, ety_t, curE, csr_se);

    // --- RGCN layer 1 ---
    k_edge_csr<<<(NENT * 64 + 255) / 256, 256, 0, stream>>>(h, h0d, offsE, csr_se, normv, agg1);
    k_mm_rrelu<<<(NENT + 63) / 64, 256, 0, stream>>>(agg1, rgcnW, NENT);
    // --- RGCN layer 2 ---
    k_edge_csr<<<(NENT * 64 + 255) / 256, 256, 0, stream>>>(agg1, h0d, offsE, csr_se, normv, agg2);
    k_mm_rrelu<<<(NENT + 63) / 64, 256, 0, stream>>>(agg2, rgcnW + HD * HD, NENT);
    // --- time gate + l2norm fusion ---
    k_final<<<(NENT + 63) / 64, 256, 0, stream>>>(agg2, h, hout, tgW, tgB, NENT);
  }
  hipMemcpyAsync(out + (size_t)TS * NENT * HD, h0bufs[(TS - 1) & 1],
                 (size_t)NR2 * HD * sizeof(float), hipMemcpyDeviceToDevice, stream);
}

// Round 3
// 2907.491 us; speedup vs baseline: 3.7643x; 1.6533x over previous
//
#include <hip/hip_runtime.h>
#include <math.h>

#define NENT 50000
#define NR2 460
#define HD 128
#define TS 8
#define EPC 200000   // edges per step
#define MPC 400000   // r_to_e entries per step
#define RSLOPE 0.22916666666666666f
#define NB_E ((NENT + 255) / 256)   // scan blocks for entity degree
#define RBLK 128                    // blocks for two-level relation CSR build

__device__ __forceinline__ float sigm(float x) { return 1.0f / (1.0f + expf(-x)); }
__device__ __forceinline__ float rrelu_f(float x) { return x >= 0.0f ? x : RSLOPE * x; }

// ---- row l2 normalize ----
__global__ __launch_bounds__(HD) void k_l2rows(const float* __restrict__ in,
                                               float* __restrict__ out) {
  int r = blockIdx.x, j = threadIdx.x;
  __shared__ float red[HD];
  float v = in[(size_t)r * HD + j];
  red[j] = v * v;
  __syncthreads();
  for (int s = HD / 2; s > 0; s >>= 1) { if (j < s) red[j] += red[j + s]; __syncthreads(); }
  float rn = 1.0f / fmaxf(sqrtf(red[0]), 1e-12f);
  out[(size_t)r * HD + j] = v * rn;
}

// ---- int histogram (entity degrees: low contention, 50k counters) ----
__global__ void k_hist(const int* __restrict__ idx, int* __restrict__ cnt, int n) {
  int i = blockIdx.x * blockDim.x + threadIdx.x;
  int gs = gridDim.x * blockDim.x;
  for (; i < n; i += gs) atomicAdd(&cnt[idx[i]], 1);
}

// ==== two-level relation CSR build (460 counters: LDS-aggregate, no contended globals) ====
__global__ __launch_bounds__(256) void k_histR2(const int* __restrict__ rseg,
                                                int* __restrict__ blkcnt) {
  __shared__ int h[NR2];
  int b = blockIdx.x, tid = threadIdx.x;
  for (int i = tid; i < NR2; i += 256) h[i] = 0;
  __syncthreads();
  int chunk = (MPC + RBLK - 1) / RBLK;
  int m0 = b * chunk, m1 = min(MPC, m0 + chunk);
  for (int m = m0 + tid; m < m1; m += 256) atomicAdd(&h[rseg[m]], 1);
  __syncthreads();
  for (int i = tid; i < NR2; i += 256) blkcnt[b * NR2 + i] = h[i];
}

__global__ __launch_bounds__(512) void k_scanR2(int* __restrict__ blkcnt,
    int* __restrict__ offsR, float* __restrict__ invc) {
  __shared__ int tot[NR2];
  __shared__ int offs[NR2 + 1];
  int tid = threadIdx.x;
  for (int r = tid; r < NR2; r += 512) {
    int s = 0;
    for (int b = 0; b < RBLK; ++b) s += blkcnt[b * NR2 + r];
    tot[r] = s;
  }
  __syncthreads();
  if (tid == 0) {
    int acc = 0;
    for (int r = 0; r < NR2; ++r) { offs[r] = acc; acc += tot[r]; }
    offs[NR2] = acc;
  }
  __syncthreads();
  for (int r = tid; r < NR2; r += 512) {
    int base = offs[r];
    for (int b = 0; b < RBLK; ++b) {
      int c = blkcnt[b * NR2 + r];
      blkcnt[b * NR2 + r] = base;   // becomes per-block base
      base += c;
    }
    offsR[r] = offs[r];
    invc[r] = tot[r] > 0 ? 1.0f / (float)tot[r] : 0.0f;
  }
  if (tid == 0) offsR[NR2] = offs[NR2];
}

__global__ __launch_bounds__(256) void k_scatterR2(const int* __restrict__ rte,
    const int* __restrict__ rseg, const int* __restrict__ blkbase,
    int* __restrict__ out) {
  __shared__ int cur[NR2];
  int b = blockIdx.x, tid = threadIdx.x;
  for (int i = tid; i < NR2; i += 256) cur[i] = blkbase[b * NR2 + i];
  __syncthreads();
  int chunk = (MPC + RBLK - 1) / RBLK;
  int m0 = b * chunk, m1 = min(MPC, m0 + chunk);
  for (int m = m0 + tid; m < m1; m += 256) {
    int r = rseg[m];
    int p = atomicAdd(&cur[r], 1);
    out[p] = rte[m];
  }
}

// ---- 3-phase exclusive scan over NENT degrees; also emits 1/deg and cursor copy ----
__global__ __launch_bounds__(256) void k_scan1(const int* __restrict__ deg,
    int* __restrict__ offs, float* __restrict__ normv, int* __restrict__ bsum) {
  __shared__ int sd[256];
  int b = blockIdx.x, tid = threadIdx.x;
  int i = b * 256 + tid;
  int v = (i < NENT) ? deg[i] : 0;
  sd[tid] = v;
  __syncthreads();
  for (int o = 1; o < 256; o <<= 1) {
    int x = (tid >= o) ? sd[tid - o] : 0;
    __syncthreads();
    sd[tid] += x;
    __syncthreads();
  }
  if (i < NENT) {
    offs[i] = sd[tid] - v;
    normv[i] = v > 0 ? 1.0f / (float)v : 0.0f;
  }
  if (tid == 255) bsum[b] = sd[255];
}

__global__ void k_scan2(int* __restrict__ bsum, int nb) {
  __shared__ int s[512];
  int tid = threadIdx.x;
  for (int i = tid; i < nb; i += blockDim.x) s[i] = bsum[i];
  __syncthreads();
  if (tid == 0) {
    int acc = 0;
    for (int i = 0; i < nb; ++i) { int t = s[i]; s[i] = acc; acc += t; }
  }
  __syncthreads();
  for (int i = tid; i < nb; i += blockDim.x) bsum[i] = s[i];
}

__global__ __launch_bounds__(256) void k_scan3(int* __restrict__ offs, int* __restrict__ cur,
                                               const int* __restrict__ bsum) {
  int b = blockIdx.x;
  int i = b * 256 + threadIdx.x;
  if (i < NENT) {
    int o = offs[i] + bsum[b];
    offs[i] = o;
    cur[i] = o;
  }
  if (b == 0 && threadIdx.x == 0) offs[NENT] = EPC;
}

// ---- edge CSR scatter (50k cursors: low contention) ----
__global__ void k_scatterE(const int* __restrict__ src, const int* __restrict__ dst,
                           const int* __restrict__ ety, int* __restrict__ cur,
                           int2* __restrict__ se) {
  int i = blockIdx.x * blockDim.x + threadIdx.x;
  int gs = gridDim.x * blockDim.x;
  for (; i < EPC; i += gs) {
    int d = dst[i];
    int p = atomicAdd(&cur[d], 1);
    se[p] = make_int2(src[i], ety[i]);
  }
}

// ---- relation partial sums via CSR gather: partials[split][rel][HD] ----
__global__ __launch_bounds__(256) void k_relmean(const float* __restrict__ h,
    const int* __restrict__ offs, const int* __restrict__ rte_csr,
    float* __restrict__ partials) {
  int rel = blockIdx.x, sp = blockIdx.y;
  int o0 = offs[rel], o1 = offs[rel + 1];
  int n = o1 - o0;
  int s0 = o0 + ((n * sp) >> 2);
  int s1 = o0 + ((n * (sp + 1)) >> 2);
  int w = threadIdx.x >> 6, lane = threadIdx.x & 63;
  const float2* h2 = (const float2*)h;
  float sx = 0.f, sy = 0.f;
  int p = s0 + w;
  for (; p + 4 < s1; p += 8) {
    int i0 = rte_csr[p];
    int i1 = rte_csr[p + 4];
    float2 v0 = h2[(size_t)i0 * 64 + lane];
    float2 v1 = h2[(size_t)i1 * 64 + lane];
    sx += v0.x + v1.x; sy += v0.y + v1.y;
  }
  for (; p < s1; p += 4) {
    int i0 = rte_csr[p];
    float2 v0 = h2[(size_t)i0 * 64 + lane];
    sx += v0.x; sy += v0.y;
  }
  __shared__ float red[4][HD];
  red[w][lane * 2] = sx;
  red[w][lane * 2 + 1] = sy;
  __syncthreads();
  if (threadIdx.x < HD) {
    int j = threadIdx.x;
    float t = red[0][j] + red[1][j] + red[2][j] + red[3][j];
    partials[((size_t)sp * NR2 + rel) * HD + j] = t;
  }
}

// ---- GRU cell + l2norm for 460 relation rows ----
__global__ __launch_bounds__(HD) void k_gru(
    const float* __restrict__ partials, const float* __restrict__ invcnt,
    const float* __restrict__ emb_rel, const float* __restrict__ h0s,
    const float* __restrict__ Wih, const float* __restrict__ Whh,
    const float* __restrict__ bih, const float* __restrict__ bhh,
    float* __restrict__ h0d) {
  int r = blockIdx.x, j = threadIdx.x;
  __shared__ __align__(16) float xr[2 * HD];
  __shared__ __align__(16) float hh[HD];
  __shared__ float red[HD];
  float inv = invcnt[r];
  xr[j] = emb_rel[r * HD + j];
  float xm = partials[(0 * NR2 + r) * HD + j] + partials[(1 * NR2 + r) * HD + j] +
             partials[(2 * NR2 + r) * HD + j] + partials[(3 * NR2 + r) * HD + j];
  xr[HD + j] = xm * inv;
  float hv0 = h0s[r * HD + j];
  hh[j] = hv0;
  __syncthreads();
  float gr = bih[j], gz = bih[HD + j], gn = bih[2 * HD + j];
  const float4* W4 = (const float4*)Wih;
  int rowA = j * 64, rowB = (j + HD) * 64, rowC = (j + 2 * HD) * 64;
  #pragma unroll 4
  for (int k4 = 0; k4 < 64; ++k4) {
    float4 xa = ((const float4*)xr)[k4];
    float4 w0 = W4[rowA + k4];
    float4 w1 = W4[rowB + k4];
    float4 w2 = W4[rowC + k4];
    gr += w0.x * xa.x + w0.y * xa.y + w0.z * xa.z + w0.w * xa.w;
    gz += w1.x * xa.x + w1.y * xa.y + w1.z * xa.z + w1.w * xa.w;
    gn += w2.x * xa.x + w2.y * xa.y + w2.z * xa.z + w2.w * xa.w;
  }
  float hr = bhh[j], hz = bhh[HD + j], hn = bhh[2 * HD + j];
  const float4* Wh4 = (const float4*)Whh;
  int rA = j * 32, rB = (j + HD) * 32, rC = (j + 2 * HD) * 32;
  #pragma unroll 4
  for (int k4 = 0; k4 < 32; ++k4) {
    float4 xa = ((const float4*)hh)[k4];
    float4 w0 = Wh4[rA + k4];
    float4 w1 = Wh4[rB + k4];
    float4 w2 = Wh4[rC + k4];
    hr += w0.x * xa.x + w0.y * xa.y + w0.z * xa.z + w0.w * xa.w;
    hz += w1.x * xa.x + w1.y * xa.y + w1.z * xa.z + w1.w * xa.w;
    hn += w2.x * xa.x + w2.y * xa.y + w2.z * xa.z + w2.w * xa.w;
  }
  float rg = sigm(gr + hr);
  float zg = sigm(gz + hz);
  float ng = tanhf(gn + rg * hn);
  float hv = (1.0f - zg) * ng + zg * hv0;
  red[j] = hv * hv;
  __syncthreads();
  for (int s = HD / 2; s > 0; s >>= 1) { if (j < s) red[j] += red[j + s]; __syncthreads(); }
  float rn = 1.0f / fmaxf(sqrtf(red[0]), 1e-12f);
  h0d[r * HD + j] = hv * rn;
}

// ---- edge aggregation via dst-CSR: one wave per dst row, register accumulate ----
__global__ __launch_bounds__(256) void k_edge_csr(
    const float* __restrict__ nh, const float* __restrict__ h0,
    const int* __restrict__ offs, const int2* __restrict__ se,
    const float* __restrict__ norm, float* __restrict__ agg) {
  int gw = (blockIdx.x * blockDim.x + threadIdx.x) >> 6;
  int lane = threadIdx.x & 63;
  if (gw >= NENT) return;
  int o0 = offs[gw], o1 = offs[gw + 1];
  const float2* nh2 = (const float2*)nh;
  const float2* h02 = (const float2*)h0;
  float sx = 0.f, sy = 0.f;
  int p = o0;
  for (; p + 2 <= o1; p += 2) {
    int2 a = se[p];
    int2 b = se[p + 1];
    float2 va = nh2[(size_t)a.x * 64 + lane];
    float2 ra = h02[(size_t)a.y * 64 + lane];
    float2 vb = nh2[(size_t)b.x * 64 + lane];
    float2 rb = h02[(size_t)b.y * 64 + lane];
    sx += (va.x + ra.x) + (vb.x + rb.x);
    sy += (va.y + ra.y) + (vb.y + rb.y);
  }
  if (p < o1) {
    int2 a = se[p];
    float2 va = nh2[(size_t)a.x * 64 + lane];
    float2 ra = h02[(size_t)a.y * 64 + lane];
    sx += va.x + ra.x;
    sy += va.y + ra.y;
  }
  float nm = norm[gw];
  ((float2*)agg)[(size_t)gw * 64 + lane] = make_float2(sx * nm, sy * nm);
}

// ---- in-place A = rrelu(A @ W), A:[nrows][128], W:[128][128] ----
__global__ __launch_bounds__(256) void k_mm_rrelu(
    float* __restrict__ A, const float* __restrict__ W, int nrows) {
  __shared__ __align__(16) float Ws[HD * HD];
  __shared__ float4 As[64 * 33];
  int tid = threadIdx.x;
  int base = blockIdx.x * 64;
  int rows = min(64, nrows - base);
  float4* Ws4 = (float4*)Ws;
  const float4* Wg4 = (const float4*)W;
  for (int i = tid; i < HD * HD / 4; i += 256) Ws4[i] = Wg4[i];
  const float4* A4 = (const float4*)A;
  for (int i = tid; i < 64 * 32; i += 256) {
    int r = i >> 5, c = i & 31;
    float4 v = make_float4(0.f, 0.f, 0.f, 0.f);
    if (r < rows) v = A4[(size_t)(base + r) * 32 + c];
    As[r * 33 + c] = v;
  }
  __syncthreads();
  int rg = tid >> 4, cg = tid & 15;
  int r0 = rg * 4, j0c = cg * 2;
  float acc[4][8];
  #pragma unroll
  for (int i = 0; i < 4; ++i)
    #pragma unroll
    for (int c = 0; c < 8; ++c) acc[i][c] = 0.f;
  for (int k4 = 0; k4 < 32; ++k4) {
    float4 a0 = As[(r0 + 0) * 33 + k4];
    float4 a1 = As[(r0 + 1) * 33 + k4];
    float4 a2 = As[(r0 + 2) * 33 + k4];
    float4 a3 = As[(r0 + 3) * 33 + k4];
    const float* pa0 = (const float*)&a0;
    const float* pa1 = (const float*)&a1;
    const float* pa2 = (const float*)&a2;
    const float* pa3 = (const float*)&a3;
    #pragma unroll
    for (int kk = 0; kk < 4; ++kk) {
      int k = k4 * 4 + kk;
      float4 wA = Ws4[k * 32 + j0c];
      float4 wB = Ws4[k * 32 + j0c + 1];
      float av[4] = {pa0[kk], pa1[kk], pa2[kk], pa3[kk]};
      #pragma unroll
      for (int i = 0; i < 4; ++i) {
        acc[i][0] += av[i] * wA.x; acc[i][1] += av[i] * wA.y;
        acc[i][2] += av[i] * wA.z; acc[i][3] += av[i] * wA.w;
        acc[i][4] += av[i] * wB.x; acc[i][5] += av[i] * wB.y;
        acc[i][6] += av[i] * wB.z; acc[i][7] += av[i] * wB.w;
      }
    }
  }
  float4* Aw4 = (float4*)A;
  #pragma unroll
  for (int i = 0; i < 4; ++i) {
    if (r0 + i < rows) {
      float4 o0, o1;
      o0.x = rrelu_f(acc[i][0]); o0.y = rrelu_f(acc[i][1]);
      o0.z = rrelu_f(acc[i][2]); o0.w = rrelu_f(acc[i][3]);
      o1.x = rrelu_f(acc[i][4]); o1.y = rrelu_f(acc[i][5]);
      o1.z = rrelu_f(acc[i][6]); o1.w = rrelu_f(acc[i][7]);
      size_t rb = (size_t)(base + r0 + i) * 32;
      Aw4[rb + j0c] = o0;
      Aw4[rb + j0c + 1] = o1;
    }
  }
}

// ---- fused: cur = l2norm(C); tw = sigmoid(Hin@Wt + b); Hout = tw*cur + (1-tw)*Hin ----
__global__ __launch_bounds__(256) void k_final(
    const float* __restrict__ C, const float* __restrict__ Hin, float* __restrict__ Hout,
    const float* __restrict__ Wt, const float* __restrict__ bias, int nrows) {
  __shared__ __align__(16) float Ws[HD * HD];
  __shared__ float4 Hs[64 * 33];
  __shared__ float4 Cs[64 * 33];
  __shared__ float pr[64][17];
  __shared__ float rn[64];
  __shared__ float bs[HD];
  int tid = threadIdx.x;
  int base = blockIdx.x * 64;
  int rows = min(64, nrows - base);
  float4* Ws4 = (float4*)Ws;
  const float4* Wg4 = (const float4*)Wt;
  for (int i = tid; i < HD * HD / 4; i += 256) Ws4[i] = Wg4[i];
  if (tid < HD) bs[tid] = bias[tid];
  const float4* H4 = (const float4*)Hin;
  const float4* C4 = (const float4*)C;
  for (int i = tid; i < 64 * 32; i += 256) {
    int r = i >> 5, c = i & 31;
    float4 h = make_float4(0.f, 0.f, 0.f, 0.f);
    float4 cc = make_float4(0.f, 0.f, 0.f, 0.f);
    if (r < rows) {
      h = H4[(size_t)(base + r) * 32 + c];
      cc = C4[(size_t)(base + r) * 32 + c];
    }
    Hs[r * 33 + c] = h;
    Cs[r * 33 + c] = cc;
  }
  __syncthreads();
  int rg = tid >> 4, cg = tid & 15;
  int r0 = rg * 4, j0 = cg * 8, j0c = cg * 2;
  const float* Cf = (const float*)Cs;
  const float* Hf = (const float*)Hs;
  #pragma unroll
  for (int i = 0; i < 4; ++i) {
    float s = 0.f;
    #pragma unroll
    for (int c = 0; c < 8; ++c) { float x = Cf[(r0 + i) * 132 + j0 + c]; s += x * x; }
    pr[r0 + i][cg] = s;
  }
  __syncthreads();
  if (tid < 64) {
    float s = 0.f;
    #pragma unroll
    for (int c = 0; c < 16; ++c) s += pr[tid][c];
    rn[tid] = 1.0f / fmaxf(sqrtf(s), 1e-12f);
  }
  __syncthreads();
  float acc[4][8];
  #pragma unroll
  for (int i = 0; i < 4; ++i)
    #pragma unroll
    for (int c = 0; c < 8; ++c) acc[i][c] = 0.f;
  for (int k4 = 0; k4 < 32; ++k4) {
    float4 a0 = Hs[(r0 + 0) * 33 + k4];
    float4 a1 = Hs[(r0 + 1) * 33 + k4];
    float4 a2 = Hs[(r0 + 2) * 33 + k4];
    float4 a3 = Hs[(r0 + 3) * 33 + k4];
    const float* pa0 = (const float*)&a0;
    const float* pa1 = (const float*)&a1;
    const float* pa2 = (const float*)&a2;
    const float* pa3 = (const float*)&a3;
    #pragma unroll
    for (int kk = 0; kk < 4; ++kk) {
      int k = k4 * 4 + kk;
      float4 wA = Ws4[k * 32 + j0c];
      float4 wB = Ws4[k * 32 + j0c + 1];
      float av[4] = {pa0[kk], pa1[kk], pa2[kk], pa3[kk]};
      #pragma unroll
      for (int i = 0; i < 4; ++i) {
        acc[i][0] += av[i] * wA.x; acc[i][1] += av[i] * wA.y;
        acc[i][2] += av[i] * wA.z; acc[i][3] += av[i] * wA.w;
        acc[i][4] += av[i] * wB.x; acc[i][5] += av[i] * wB.y;
        acc[i][6] += av[i] * wB.z; acc[i][7] += av[i] * wB.w;
      }
    }
  }
  float4* O4 = (float4*)Hout;
  #pragma unroll
  for (int i = 0; i < 4; ++i) {
    if (r0 + i < rows) {
      int r = r0 + i;
      float rnv = rn[r];
      float o[8];
      #pragma unroll
      for (int c = 0; c < 8; ++c) {
        float tw = sigm(acc[i][c] + bs[j0 + c]);
        float hval = Hf[r * 132 + j0 + c];
        float chv = Cf[r * 132 + j0 + c] * rnv;
        o[c] = tw * chv + (1.0f - tw) * hval;
      }
      size_t rb = (size_t)(base + r) * 32;
      O4[rb + j0c] = make_float4(o[0], o[1], o[2], o[3]);
      O4[rb + j0c + 1] = make_float4(o[4], o[5], o[6], o[7]);
    }
  }
}

extern "C" void kernel_launch(void* const* d_in, const int* in_sizes, int n_in,
                              void* d_out, int out_size, void* d_ws, size_t ws_size,
                              hipStream_t stream) {
  const int* src    = (const int*)d_in[0];
  const int* dst    = (const int*)d_in[1];
  const int* etype  = (const int*)d_in[2];
  const int* rte    = (const int*)d_in[3];
  const int* rseg   = (const int*)d_in[4];
  const float* dyn  = (const float*)d_in[5];
  const float* emb_rel = (const float*)d_in[6];
  const float* W_ih = (const float*)d_in[7];
  const float* W_hh = (const float*)d_in[8];
  const float* b_ih = (const float*)d_in[9];
  const float* b_hh = (const float*)d_in[10];
  const float* rgcnW = (const float*)d_in[11];
  const float* tgW  = (const float*)d_in[12];
  const float* tgB  = (const float*)d_in[13];
  float* out = (float*)d_out;
  (void)in_sizes; (void)n_in; (void)out_size; (void)ws_size;

  float* ws = (float*)d_ws;
  size_t off = 0;
  float* agg1   = ws + off; off += (size_t)NENT * HD;
  float* agg2   = ws + off; off += (size_t)NENT * HD;
  float* parts  = ws + off; off += (size_t)4 * NR2 * HD;
  float* h0a    = ws + off; off += (size_t)NR2 * HD;
  float* h0b    = ws + off; off += (size_t)NR2 * HD;
  float* normv  = ws + off; off += NENT;
  float* invcnt = ws + off; off += NR2;
  off = (off + 1) & ~(size_t)1;   // 8B alignment for int2
  int2* csr_se  = (int2*)(ws + off); off += (size_t)2 * EPC;
  int* csr_rte  = (int*)(ws + off);  off += MPC;
  int* degE     = (int*)(ws + off);  off += NENT;
  int* offsE    = (int*)(ws + off);  off += NENT + 2;
  int* curE     = (int*)(ws + off);  off += NENT;
  int* bsum     = (int*)(ws + off);  off += NB_E;
  int* blkcntR  = (int*)(ws + off);  off += (size_t)RBLK * NR2;
  int* offsR    = (int*)(ws + off);  off += NR2 + 2;

  // h_init = l2norm(dynamic_emb) -> d_out slot 0 doubles as first h
  k_l2rows<<<NENT, HD, 0, stream>>>(dyn, out);

  float* h0bufs[2] = {h0a, h0b};
  for (int t = 0; t < TS; ++t) {
    const float* h = out + (size_t)(t == 0 ? 0 : (t - 1)) * NENT * HD;
    float* hout = out + (size_t)t * NENT * HD;
    const float* h0s = (t == 0) ? emb_rel : h0bufs[(t - 1) & 1];
    float* h0d = h0bufs[t & 1];
    const int* src_t = src + (size_t)t * EPC;
    const int* dst_t = dst + (size_t)t * EPC;
    const int* ety_t = etype + (size_t)t * EPC;
    const int* rte_t = rte + (size_t)t * MPC;
    const int* rsg_t = rseg + (size_t)t * MPC;

    // --- relation CSR build (two-level, no contended global atomics) ---
    k_histR2<<<RBLK, 256, 0, stream>>>(rsg_t, blkcntR);
    k_scanR2<<<1, 512, 0, stream>>>(blkcntR, offsR, invcnt);
    k_scatterR2<<<RBLK, 256, 0, stream>>>(rte_t, rsg_t, blkcntR, csr_rte);
    k_relmean<<<dim3(NR2, 4), 256, 0, stream>>>(h, offsR, csr_rte, parts);
    k_gru<<<NR2, HD, 0, stream>>>(parts, invcnt, emb_rel, h0s, W_ih, W_hh, b_ih, b_hh, h0d);

    // --- edge CSR build ---
    hipMemsetAsync(degE, 0, NENT * sizeof(int), stream);
    k_hist<<<256, 256, 0, stream>>>(dst_t, degE, EPC);
    k_scan1<<<NB_E, 256, 0, stream>>>(degE, offsE, normv, bsum);
    k_scan2<<<1, 256, 0, stream>>>(bsum, NB_E);
    k_scan3<<<NB_E, 256, 0, stream>>>(offsE, curE, bsum);
    k_scatterE<<<256, 256, 0, stream>>>(src_t, dst_t, ety_t, curE, csr_se);

    // --- RGCN layer 1 ---
    k_edge_csr<<<(NENT * 64 + 255) / 256, 256, 0, stream>>>(h, h0d, offsE, csr_se, normv, agg1);
    k_mm_rrelu<<<(NENT + 63) / 64, 256, 0, stream>>>(agg1, rgcnW, NENT);
    // --- RGCN layer 2 ---
    k_edge_csr<<<(NENT * 64 + 255) / 256, 256, 0, stream>>>(agg1, h0d, offsE, csr_se, normv, agg2);
    k_mm_rrelu<<<(NENT + 63) / 64, 256, 0, stream>>>(agg2, rgcnW + HD * HD, NENT);
    // --- time gate + l2norm fusion ---
    k_final<<<(NENT + 63) / 64, 256, 0, stream>>>(agg2, h, hout, tgW, tgB, NENT);
  }
  hipMemcpyAsync(out + (size_t)TS * NENT * HD, h0bufs[(TS - 1) & 1],
                 (size_t)NR2 * HD * sizeof(float), hipMemcpyDeviceToDevice, stream);
}

// Round 4
// 2666.754 us; speedup vs baseline: 4.1041x; 1.0903x over previous
//
#include <hip/hip_runtime.h>
#include <math.h>

#define NENT 50000
#define NR2 460
#define HD 128
#define TS 8
#define EPC 200000   // edges per step
#define MPC 400000   // r_to_e entries per step
#define RSLOPE 0.22916666666666666f
#define RBLK 128                    // blocks per step for two-level relation CSR build
#define NTOT (TS * NENT)            // 400000 flattened (t, entity)
#define NB8 ((NTOT + 255) / 256)    // 1563 scan blocks
#define SCAN2_PER ((NB8 + 255) / 256)  // 7
#define RSP 8                       // relmean splits

__device__ __forceinline__ float sigm(float x) { return 1.0f / (1.0f + expf(-x)); }
__device__ __forceinline__ float rrelu_f(float x) { return x >= 0.0f ? x : RSLOPE * x; }

// ---- row l2 normalize ----
__global__ __launch_bounds__(HD) void k_l2rows(const float* __restrict__ in,
                                               float* __restrict__ out) {
  int r = blockIdx.x, j = threadIdx.x;
  __shared__ float red[HD];
  float v = in[(size_t)r * HD + j];
  red[j] = v * v;
  __syncthreads();
  for (int s = HD / 2; s > 0; s >>= 1) { if (j < s) red[j] += red[j + s]; __syncthreads(); }
  float rn = 1.0f / fmaxf(sqrtf(red[0]), 1e-12f);
  out[(size_t)r * HD + j] = v * rn;
}

// ---- batched histogram: cnt[(i/per_t)*stride + idx[i]] += 1 ----
__global__ void k_hist(const int* __restrict__ idx, int* __restrict__ cnt,
                       int n, int per_t, int stride) {
  int i = blockIdx.x * blockDim.x + threadIdx.x;
  int gs = gridDim.x * blockDim.x;
  for (; i < n; i += gs) atomicAdd(&cnt[(i / per_t) * stride + idx[i]], 1);
}

// ==== batched two-level relation CSR build ====
__global__ __launch_bounds__(256) void k_histR2(const int* __restrict__ rseg,
                                                int* __restrict__ blkcnt) {
  __shared__ int h[NR2];
  int b = blockIdx.x, t = blockIdx.y, tid = threadIdx.x;
  for (int i = tid; i < NR2; i += 256) h[i] = 0;
  __syncthreads();
  const int* rs = rseg + (size_t)t * MPC;
  int chunk = (MPC + RBLK - 1) / RBLK;
  int m0 = b * chunk, m1 = min(MPC, m0 + chunk);
  for (int m = m0 + tid; m < m1; m += 256) atomicAdd(&h[rs[m]], 1);
  __syncthreads();
  for (int i = tid; i < NR2; i += 256) blkcnt[((size_t)(t * RBLK + b)) * NR2 + i] = h[i];
}

__global__ __launch_bounds__(512) void k_scanR2(int* __restrict__ blkcnt,
    int* __restrict__ offsR, float* __restrict__ invc) {
  __shared__ int tot[TS * NR2];
  __shared__ int ofs[TS * NR2];
  int tid = threadIdx.x;
  for (int idx = tid; idx < TS * NR2; idx += 512) {
    int t = idx / NR2, r = idx - t * NR2;
    int s = 0;
    for (int b = 0; b < RBLK; ++b) s += blkcnt[((size_t)(t * RBLK + b)) * NR2 + r];
    tot[idx] = s;
  }
  __syncthreads();
  if (tid < TS) {   // per-step serial scan; step t starts at t*MPC
    int acc = tid * MPC;
    for (int r = 0; r < NR2; ++r) { ofs[tid * NR2 + r] = acc; acc += tot[tid * NR2 + r]; }
  }
  __syncthreads();
  for (int idx = tid; idx < TS * NR2; idx += 512) {
    int t = idx / NR2, r = idx - t * NR2;
    int base = ofs[idx];
    for (int b = 0; b < RBLK; ++b) {
      size_t bi = ((size_t)(t * RBLK + b)) * NR2 + r;
      int c = blkcnt[bi];
      blkcnt[bi] = base;   // becomes per-block scatter base
      base += c;
    }
    offsR[idx] = ofs[idx];
    invc[idx] = tot[idx] > 0 ? 1.0f / (float)tot[idx] : 0.0f;
  }
  if (tid == 0) offsR[TS * NR2] = TS * MPC;
}

__global__ __launch_bounds__(256) void k_scatterR2(const int* __restrict__ rte,
    const int* __restrict__ rseg, const int* __restrict__ blkbase,
    int* __restrict__ out) {
  __shared__ int cur[NR2];
  int b = blockIdx.x, t = blockIdx.y, tid = threadIdx.x;
  for (int i = tid; i < NR2; i += 256) cur[i] = blkbase[((size_t)(t * RBLK + b)) * NR2 + i];
  __syncthreads();
  const int* rs = rseg + (size_t)t * MPC;
  const int* re = rte + (size_t)t * MPC;
  int chunk = (MPC + RBLK - 1) / RBLK;
  int m0 = b * chunk, m1 = min(MPC, m0 + chunk);
  for (int m = m0 + tid; m < m1; m += 256) {
    int r = rs[m];
    int p = atomicAdd(&cur[r], 1);
    out[p] = re[m];
  }
}

// ---- flat 3-phase exclusive scan over TS*NENT degrees; emits 1/deg + cursor ----
__global__ __launch_bounds__(256) void k_scan1(const int* __restrict__ deg,
    int* __restrict__ offs, float* __restrict__ normv, int* __restrict__ bsum) {
  __shared__ int sd[256];
  int b = blockIdx.x, tid = threadIdx.x;
  int i = b * 256 + tid;
  int v = (i < NTOT) ? deg[i] : 0;
  sd[tid] = v;
  __syncthreads();
  for (int o = 1; o < 256; o <<= 1) {
    int x = (tid >= o) ? sd[tid - o] : 0;
    __syncthreads();
    sd[tid] += x;
    __syncthreads();
  }
  if (i < NTOT) {
    offs[i] = sd[tid] - v;
    normv[i] = v > 0 ? 1.0f / (float)v : 0.0f;
  }
  if (tid == 255) bsum[b] = sd[255];
}

__global__ __launch_bounds__(256) void k_scan2(int* __restrict__ bsum) {
  __shared__ int part[256];
  int tid = threadIdx.x;
  int base = tid * SCAN2_PER;
  int local[SCAN2_PER];
  int s = 0;
  #pragma unroll
  for (int k = 0; k < SCAN2_PER; ++k) {
    int v = (base + k < NB8) ? bsum[base + k] : 0;
    local[k] = s;
    s += v;
  }
  part[tid] = s;
  __syncthreads();
  for (int o = 1; o < 256; o <<= 1) {
    int x = (tid >= o) ? part[tid - o] : 0;
    __syncthreads();
    part[tid] += x;
    __syncthreads();
  }
  int pre = (tid > 0) ? part[tid - 1] : 0;
  #pragma unroll
  for (int k = 0; k < SCAN2_PER; ++k)
    if (base + k < NB8) bsum[base + k] = pre + local[k];
}

__global__ __launch_bounds__(256) void k_scan3(int* __restrict__ offs, int* __restrict__ cur,
                                               const int* __restrict__ bsum) {
  int b = blockIdx.x;
  int i = b * 256 + threadIdx.x;
  if (i < NTOT) {
    int o = offs[i] + bsum[b];
    offs[i] = o;
    cur[i] = o;
  }
  if (b == 0 && threadIdx.x == 0) offs[NTOT] = TS * EPC;
}

// ---- batched edge CSR scatter (TS*NENT cursors: low contention) ----
__global__ void k_scatterE(const int* __restrict__ src, const int* __restrict__ dst,
                           const int* __restrict__ ety, int* __restrict__ cur,
                           int2* __restrict__ se) {
  int i = blockIdx.x * blockDim.x + threadIdx.x;
  int gs = gridDim.x * blockDim.x;
  for (; i < TS * EPC; i += gs) {
    int t = i / EPC;
    int d = dst[i];
    int p = atomicAdd(&cur[t * NENT + d], 1);
    se[p] = make_int2(src[i], ety[i]);
  }
}

// ---- relation partial sums via CSR gather: partials[split][rel][HD] ----
__global__ __launch_bounds__(256) void k_relmean(const float* __restrict__ h,
    const int* __restrict__ offs, const int* __restrict__ rte_csr,
    float* __restrict__ partials) {
  int rel = blockIdx.x, sp = blockIdx.y;
  int o0 = offs[rel], o1 = offs[rel + 1];
  int n = o1 - o0;
  int s0 = o0 + ((n * sp) >> 3);
  int s1 = o0 + ((n * (sp + 1)) >> 3);
  int w = threadIdx.x >> 6, lane = threadIdx.x & 63;
  const float2* h2 = (const float2*)h;
  float sx = 0.f, sy = 0.f;
  int p = s0 + w;
  for (; p + 4 < s1; p += 8) {
    int i0 = rte_csr[p];
    int i1 = rte_csr[p + 4];
    float2 v0 = h2[(size_t)i0 * 64 + lane];
    float2 v1 = h2[(size_t)i1 * 64 + lane];
    sx += v0.x + v1.x; sy += v0.y + v1.y;
  }
  for (; p < s1; p += 4) {
    int i0 = rte_csr[p];
    float2 v0 = h2[(size_t)i0 * 64 + lane];
    sx += v0.x; sy += v0.y;
  }
  __shared__ float red[4][HD];
  red[w][lane * 2] = sx;
  red[w][lane * 2 + 1] = sy;
  __syncthreads();
  if (threadIdx.x < HD) {
    int j = threadIdx.x;
    float t = red[0][j] + red[1][j] + red[2][j] + red[3][j];
    partials[((size_t)sp * NR2 + rel) * HD + j] = t;
  }
}

// ---- GRU cell + l2norm for 460 relation rows ----
__global__ __launch_bounds__(HD) void k_gru(
    const float* __restrict__ partials, const float* __restrict__ invcnt,
    const float* __restrict__ emb_rel, const float* __restrict__ h0s,
    const float* __restrict__ Wih, const float* __restrict__ Whh,
    const float* __restrict__ bih, const float* __restrict__ bhh,
    float* __restrict__ h0d) {
  int r = blockIdx.x, j = threadIdx.x;
  __shared__ __align__(16) float xr[2 * HD];
  __shared__ __align__(16) float hh[HD];
  __shared__ float red[HD];
  float inv = invcnt[r];
  xr[j] = emb_rel[r * HD + j];
  float xm = 0.f;
  #pragma unroll
  for (int sp = 0; sp < RSP; ++sp) xm += partials[((size_t)sp * NR2 + r) * HD + j];
  xr[HD + j] = xm * inv;
  float hv0 = h0s[r * HD + j];
  hh[j] = hv0;
  __syncthreads();
  float gr = bih[j], gz = bih[HD + j], gn = bih[2 * HD + j];
  const float4* W4 = (const float4*)Wih;
  int rowA = j * 64, rowB = (j + HD) * 64, rowC = (j + 2 * HD) * 64;
  #pragma unroll 4
  for (int k4 = 0; k4 < 64; ++k4) {
    float4 xa = ((const float4*)xr)[k4];
    float4 w0 = W4[rowA + k4];
    float4 w1 = W4[rowB + k4];
    float4 w2 = W4[rowC + k4];
    gr += w0.x * xa.x + w0.y * xa.y + w0.z * xa.z + w0.w * xa.w;
    gz += w1.x * xa.x + w1.y * xa.y + w1.z * xa.z + w1.w * xa.w;
    gn += w2.x * xa.x + w2.y * xa.y + w2.z * xa.z + w2.w * xa.w;
  }
  float hr = bhh[j], hz = bhh[HD + j], hn = bhh[2 * HD + j];
  const float4* Wh4 = (const float4*)Whh;
  int rA = j * 32, rB = (j + HD) * 32, rC = (j + 2 * HD) * 32;
  #pragma unroll 4
  for (int k4 = 0; k4 < 32; ++k4) {
    float4 xa = ((const float4*)hh)[k4];
    float4 w0 = Wh4[rA + k4];
    float4 w1 = Wh4[rB + k4];
    float4 w2 = Wh4[rC + k4];
    hr += w0.x * xa.x + w0.y * xa.y + w0.z * xa.z + w0.w * xa.w;
    hz += w1.x * xa.x + w1.y * xa.y + w1.z * xa.z + w1.w * xa.w;
    hn += w2.x * xa.x + w2.y * xa.y + w2.z * xa.z + w2.w * xa.w;
  }
  float rg = sigm(gr + hr);
  float zg = sigm(gz + hz);
  float ng = tanhf(gn + rg * hn);
  float hv = (1.0f - zg) * ng + zg * hv0;
  red[j] = hv * hv;
  __syncthreads();
  for (int s = HD / 2; s > 0; s >>= 1) { if (j < s) red[j] += red[j + s]; __syncthreads(); }
  float rn = 1.0f / fmaxf(sqrtf(red[0]), 1e-12f);
  h0d[r * HD + j] = hv * rn;
}

// ---- edge aggregation via dst-CSR: one wave per dst row, register accumulate ----
__global__ __launch_bounds__(256) void k_edge_csr(
    const float* __restrict__ nh, const float* __restrict__ h0,
    const int* __restrict__ offs, const int2* __restrict__ se,
    const float* __restrict__ norm, float* __restrict__ agg) {
  int gw = (blockIdx.x * blockDim.x + threadIdx.x) >> 6;
  int lane = threadIdx.x & 63;
  if (gw >= NENT) return;
  int o0 = offs[gw], o1 = offs[gw + 1];
  const float2* nh2 = (const float2*)nh;
  const float2* h02 = (const float2*)h0;
  float sx = 0.f, sy = 0.f;
  int p = o0;
  for (; p + 2 <= o1; p += 2) {
    int2 a = se[p];
    int2 b = se[p + 1];
    float2 va = nh2[(size_t)a.x * 64 + lane];
    float2 ra = h02[(size_t)a.y * 64 + lane];
    float2 vb = nh2[(size_t)b.x * 64 + lane];
    float2 rb = h02[(size_t)b.y * 64 + lane];
    sx += (va.x + ra.x) + (vb.x + rb.x);
    sy += (va.y + ra.y) + (vb.y + rb.y);
  }
  if (p < o1) {
    int2 a = se[p];
    float2 va = nh2[(size_t)a.x * 64 + lane];
    float2 ra = h02[(size_t)a.y * 64 + lane];
    sx += va.x + ra.x;
    sy += va.y + ra.y;
  }
  float nm = norm[gw];
  ((float2*)agg)[(size_t)gw * 64 + lane] = make_float2(sx * nm, sy * nm);
}

// ---- in-place A = rrelu(A @ W), A:[nrows][128], W:[128][128] ----
__global__ __launch_bounds__(256) void k_mm_rrelu(
    float* __restrict__ A, const float* __restrict__ W, int nrows) {
  __shared__ __align__(16) float Ws[HD * HD];
  __shared__ float4 As[64 * 33];
  int tid = threadIdx.x;
  int base = blockIdx.x * 64;
  int rows = min(64, nrows - base);
  float4* Ws4 = (float4*)Ws;
  const float4* Wg4 = (const float4*)W;
  for (int i = tid; i < HD * HD / 4; i += 256) Ws4[i] = Wg4[i];
  const float4* A4 = (const float4*)A;
  for (int i = tid; i < 64 * 32; i += 256) {
    int r = i >> 5, c = i & 31;
    float4 v = make_float4(0.f, 0.f, 0.f, 0.f);
    if (r < rows) v = A4[(size_t)(base + r) * 32 + c];
    As[r * 33 + c] = v;
  }
  __syncthreads();
  int rg = tid >> 4, cg = tid & 15;
  int r0 = rg * 4, j0c = cg * 2;
  float acc[4][8];
  #pragma unroll
  for (int i = 0; i < 4; ++i)
    #pragma unroll
    for (int c = 0; c < 8; ++c) acc[i][c] = 0.f;
  for (int k4 = 0; k4 < 32; ++k4) {
    float4 a0 = As[(r0 + 0) * 33 + k4];
    float4 a1 = As[(r0 + 1) * 33 + k4];
    float4 a2 = As[(r0 + 2) * 33 + k4];
    float4 a3 = As[(r0 + 3) * 33 + k4];
    const float* pa0 = (const float*)&a0;
    const float* pa1 = (const float*)&a1;
    const float* pa2 = (const float*)&a2;
    const float* pa3 = (const float*)&a3;
    #pragma unroll
    for (int kk = 0; kk < 4; ++kk) {
      int k = k4 * 4 + kk;
      float4 wA = Ws4[k * 32 + j0c];
      float4 wB = Ws4[k * 32 + j0c + 1];
      float av[4] = {pa0[kk], pa1[kk], pa2[kk], pa3[kk]};
      #pragma unroll
      for (int i = 0; i < 4; ++i) {
        acc[i][0] += av[i] * wA.x; acc[i][1] += av[i] * wA.y;
        acc[i][2] += av[i] * wA.z; acc[i][3] += av[i] * wA.w;
        acc[i][4] += av[i] * wB.x; acc[i][5] += av[i] * wB.y;
        acc[i][6] += av[i] * wB.z; acc[i][7] += av[i] * wB.w;
      }
    }
  }
  float4* Aw4 = (float4*)A;
  #pragma unroll
  for (int i = 0; i < 4; ++i) {
    if (r0 + i < rows) {
      float4 o0, o1;
      o0.x = rrelu_f(acc[i][0]); o0.y = rrelu_f(acc[i][1]);
      o0.z = rrelu_f(acc[i][2]); o0.w = rrelu_f(acc[i][3]);
      o1.x = rrelu_f(acc[i][4]); o1.y = rrelu_f(acc[i][5]);
      o1.z = rrelu_f(acc[i][6]); o1.w = rrelu_f(acc[i][7]);
      size_t rb = (size_t)(base + r0 + i) * 32;
      Aw4[rb + j0c] = o0;
      Aw4[rb + j0c + 1] = o1;
    }
  }
}

// ---- fused: cur = l2norm(C); tw = sigmoid(Hin@Wt + b); Hout = tw*cur + (1-tw)*Hin ----
__global__ __launch_bounds__(256) void k_final(
    const float* __restrict__ C, const float* __restrict__ Hin, float* __restrict__ Hout,
    const float* __restrict__ Wt, const float* __restrict__ bias, int nrows) {
  __shared__ __align__(16) float Ws[HD * HD];
  __shared__ float4 Hs[64 * 33];
  __shared__ float4 Cs[64 * 33];
  __shared__ float pr[64][17];
  __shared__ float rn[64];
  __shared__ float bs[HD];
  int tid = threadIdx.x;
  int base = blockIdx.x * 64;
  int rows = min(64, nrows - base);
  float4* Ws4 = (float4*)Ws;
  const float4* Wg4 = (const float4*)Wt;
  for (int i = tid; i < HD * HD / 4; i += 256) Ws4[i] = Wg4[i];
  if (tid < HD) bs[tid] = bias[tid];
  const float4* H4 = (const float4*)Hin;
  const float4* C4 = (const float4*)C;
  for (int i = tid; i < 64 * 32; i += 256) {
    int r = i >> 5, c = i & 31;
    float4 h = make_float4(0.f, 0.f, 0.f, 0.f);
    float4 cc = make_float4(0.f, 0.f, 0.f, 0.f);
    if (r < rows) {
      h = H4[(size_t)(base + r) * 32 + c];
      cc = C4[(size_t)(base + r) * 32 + c];
    }
    Hs[r * 33 + c] = h;
    Cs[r * 33 + c] = cc;
  }
  __syncthreads();
  int rg = tid >> 4, cg = tid & 15;
  int r0 = rg * 4, j0 = cg * 8, j0c = cg * 2;
  const float* Cf = (const float*)Cs;
  const float* Hf = (const float*)Hs;
  #pragma unroll
  for (int i = 0; i < 4; ++i) {
    float s = 0.f;
    #pragma unroll
    for (int c = 0; c < 8; ++c) { float x = Cf[(r0 + i) * 132 + j0 + c]; s += x * x; }
    pr[r0 + i][cg] = s;
  }
  __syncthreads();
  if (tid < 64) {
    float s = 0.f;
    #pragma unroll
    for (int c = 0; c < 16; ++c) s += pr[tid][c];
    rn[tid] = 1.0f / fmaxf(sqrtf(s), 1e-12f);
  }
  __syncthreads();
  float acc[4][8];
  #pragma unroll
  for (int i = 0; i < 4; ++i)
    #pragma unroll
    for (int c = 0; c < 8; ++c) acc[i][c] = 0.f;
  for (int k4 = 0; k4 < 32; ++k4) {
    float4 a0 = Hs[(r0 + 0) * 33 + k4];
    float4 a1 = Hs[(r0 + 1) * 33 + k4];
    float4 a2 = Hs[(r0 + 2) * 33 + k4];
    float4 a3 = Hs[(r0 + 3) * 33 + k4];
    const float* pa0 = (const float*)&a0;
    const float* pa1 = (const float*)&a1;
    const float* pa2 = (const float*)&a2;
    const float* pa3 = (const float*)&a3;
    #pragma unroll
    for (int kk = 0; kk < 4; ++kk) {
      int k = k4 * 4 + kk;
      float4 wA = Ws4[k * 32 + j0c];
      float4 wB = Ws4[k * 32 + j0c + 1];
      float av[4] = {pa0[kk], pa1[kk], pa2[kk], pa3[kk]};
      #pragma unroll
      for (int i = 0; i < 4; ++i) {
        acc[i][0] += av[i] * wA.x; acc[i][1] += av[i] * wA.y;
        acc[i][2] += av[i] * wA.z; acc[i][3] += av[i] * wA.w;
        acc[i][4] += av[i] * wB.x; acc[i][5] += av[i] * wB.y;
        acc[i][6] += av[i] * wB.z; acc[i][7] += av[i] * wB.w;
      }
    }
  }
  float4* O4 = (float4*)Hout;
  #pragma unroll
  for (int i = 0; i < 4; ++i) {
    if (r0 + i < rows) {
      int r = r0 + i;
      float rnv = rn[r];
      float o[8];
      #pragma unroll
      for (int c = 0; c < 8; ++c) {
        float tw = sigm(acc[i][c] + bs[j0 + c]);
        float hval = Hf[r * 132 + j0 + c];
        float chv = Cf[r * 132 + j0 + c] * rnv;
        o[c] = tw * chv + (1.0f - tw) * hval;
      }
      size_t rb = (size_t)(base + r) * 32;
      O4[rb + j0c] = make_float4(o[0], o[1], o[2], o[3]);
      O4[rb + j0c + 1] = make_float4(o[4], o[5], o[6], o[7]);
    }
  }
}

extern "C" void kernel_launch(void* const* d_in, const int* in_sizes, int n_in,
                              void* d_out, int out_size, void* d_ws, size_t ws_size,
                              hipStream_t stream) {
  const int* src    = (const int*)d_in[0];
  const int* dst    = (const int*)d_in[1];
  const int* etype  = (const int*)d_in[2];
  const int* rte    = (const int*)d_in[3];
  const int* rseg   = (const int*)d_in[4];
  const float* dyn  = (const float*)d_in[5];
  const float* emb_rel = (const float*)d_in[6];
  const float* W_ih = (const float*)d_in[7];
  const float* W_hh = (const float*)d_in[8];
  const float* b_ih = (const float*)d_in[9];
  const float* b_hh = (const float*)d_in[10];
  const float* rgcnW = (const float*)d_in[11];
  const float* tgW  = (const float*)d_in[12];
  const float* tgB  = (const float*)d_in[13];
  float* out = (float*)d_out;
  (void)in_sizes; (void)n_in; (void)out_size; (void)ws_size;

  float* ws = (float*)d_ws;
  size_t off = 0;
  float* agg1    = ws + off; off += (size_t)NENT * HD;
  float* agg2    = ws + off; off += (size_t)NENT * HD;
  float* parts   = ws + off; off += (size_t)RSP * NR2 * HD;
  float* h0a     = ws + off; off += (size_t)NR2 * HD;
  float* h0b     = ws + off; off += (size_t)NR2 * HD;
  float* normv8  = ws + off; off += NTOT;
  float* invc8   = ws + off; off += TS * NR2;
  off = (off + 1) & ~(size_t)1;   // 8B alignment for int2
  int2* csr_se8  = (int2*)(ws + off); off += (size_t)2 * TS * EPC;
  int* csr_rte8  = (int*)(ws + off);  off += (size_t)TS * MPC;
  int* degE8     = (int*)(ws + off);  off += NTOT;
  int* offsE8    = (int*)(ws + off);  off += NTOT + 2;
  int* curE8     = (int*)(ws + off);  off += NTOT;
  int* bsum      = (int*)(ws + off);  off += NB8;
  int* blkcntR8  = (int*)(ws + off);  off += (size_t)TS * RBLK * NR2;
  int* offsR8    = (int*)(ws + off);  off += TS * NR2 + 2;

  // ===== hoisted, batched CSR builds for all TS steps (input-only) =====
  hipMemsetAsync(degE8, 0, (size_t)NTOT * sizeof(int), stream);
  k_hist<<<2048, 256, 0, stream>>>(dst, degE8, TS * EPC, EPC, NENT);
  k_scan1<<<NB8, 256, 0, stream>>>(degE8, offsE8, normv8, bsum);
  k_scan2<<<1, 256, 0, stream>>>(bsum);
  k_scan3<<<NB8, 256, 0, stream>>>(offsE8, curE8, bsum);
  k_scatterE<<<2048, 256, 0, stream>>>(src, dst, etype, curE8, csr_se8);
  k_histR2<<<dim3(RBLK, TS), 256, 0, stream>>>(rseg, blkcntR8);
  k_scanR2<<<1, 512, 0, stream>>>(blkcntR8, offsR8, invc8);
  k_scatterR2<<<dim3(RBLK, TS), 256, 0, stream>>>(rte, rseg, blkcntR8, csr_rte8);

  // h_init = l2norm(dynamic_emb) -> d_out slot 0 doubles as first h
  k_l2rows<<<NENT, HD, 0, stream>>>(dyn, out);

  float* h0bufs[2] = {h0a, h0b};
  for (int t = 0; t < TS; ++t) {
    const float* h = out + (size_t)(t == 0 ? 0 : (t - 1)) * NENT * HD;
    float* hout = out + (size_t)t * NENT * HD;
    const float* h0s = (t == 0) ? emb_rel : h0bufs[(t - 1) & 1];
    float* h0d = h0bufs[t & 1];

    k_relmean<<<dim3(NR2, RSP), 256, 0, stream>>>(h, offsR8 + t * NR2, csr_rte8, parts);
    k_gru<<<NR2, HD, 0, stream>>>(parts, invc8 + t * NR2, emb_rel, h0s,
                                  W_ih, W_hh, b_ih, b_hh, h0d);

    k_edge_csr<<<(NENT * 64 + 255) / 256, 256, 0, stream>>>(
        h, h0d, offsE8 + t * NENT, csr_se8, normv8 + t * NENT, agg1);
    k_mm_rrelu<<<(NENT + 63) / 64, 256, 0, stream>>>(agg1, rgcnW, NENT);
    k_edge_csr<<<(NENT * 64 + 255) / 256, 256, 0, stream>>>(
        agg1, h0d, offsE8 + t * NENT, csr_se8, normv8 + t * NENT, agg2);
    k_mm_rrelu<<<(NENT + 63) / 64, 256, 0, stream>>>(agg2, rgcnW + HD * HD, NENT);

    k_final<<<(NENT + 63) / 64, 256, 0, stream>>>(agg2, h, hout, tgW, tgB, NENT);
  }
  hipMemcpyAsync(out + (size_t)TS * NENT * HD, h0bufs[(TS - 1) & 1],
                 (size_t)NR2 * HD * sizeof(float), hipMemcpyDeviceToDevice, stream);
}

// Round 5
// 1786.069 us; speedup vs baseline: 6.1277x; 1.4931x over previous
//
#include <hip/hip_runtime.h>
#include <math.h>

#define NENT 50000
#define NR2 460
#define HD 128
#define TS 8
#define EPC 200000   // edges per step
#define MPC 400000   // r_to_e entries per step
#define RSLOPE 0.22916666666666666f
#define RBLK 128                    // blocks per step for two-level relation CSR build
#define NTOT (TS * NENT)            // 400000 flattened (t, entity)
#define NB8 ((NTOT + 255) / 256)    // 1563 scan blocks
#define SCAN2_PER ((NB8 + 255) / 256)  // 7
#define RSP 8                       // relmean splits

typedef __attribute__((ext_vector_type(8))) short bfrag;   // 8 bf16 (4 VGPR)
typedef __attribute__((ext_vector_type(4))) float facc;    // mfma f32x4 acc

__device__ __forceinline__ float sigm(float x) { return 1.0f / (1.0f + expf(-x)); }
__device__ __forceinline__ float rrelu_f(float x) { return x >= 0.0f ? x : RSLOPE * x; }
__device__ __forceinline__ unsigned short f2bf_rne(float x) {
  unsigned u = __float_as_uint(x);
  unsigned r = (u + 0x7FFFu + ((u >> 16) & 1u)) >> 16;
  return (unsigned short)r;
}
__device__ __forceinline__ float bf2f(unsigned short b) {
  return __uint_as_float(((unsigned)b) << 16);
}

// ---- row l2 normalize ----
__global__ __launch_bounds__(HD) void k_l2rows(const float* __restrict__ in,
                                               float* __restrict__ out) {
  int r = blockIdx.x, j = threadIdx.x;
  __shared__ float red[HD];
  float v = in[(size_t)r * HD + j];
  red[j] = v * v;
  __syncthreads();
  for (int s = HD / 2; s > 0; s >>= 1) { if (j < s) red[j] += red[j + s]; __syncthreads(); }
  float rn = 1.0f / fmaxf(sqrtf(red[0]), 1e-12f);
  out[(size_t)r * HD + j] = v * rn;
}

// ---- batched histogram ----
__global__ void k_hist(const int* __restrict__ idx, int* __restrict__ cnt,
                       int n, int per_t, int stride) {
  int i = blockIdx.x * blockDim.x + threadIdx.x;
  int gs = gridDim.x * blockDim.x;
  for (; i < n; i += gs) atomicAdd(&cnt[(i / per_t) * stride + idx[i]], 1);
}

// ==== batched two-level relation CSR build ====
__global__ __launch_bounds__(256) void k_histR2(const int* __restrict__ rseg,
                                                int* __restrict__ blkcnt) {
  __shared__ int h[NR2];
  int b = blockIdx.x, t = blockIdx.y, tid = threadIdx.x;
  for (int i = tid; i < NR2; i += 256) h[i] = 0;
  __syncthreads();
  const int* rs = rseg + (size_t)t * MPC;
  int chunk = (MPC + RBLK - 1) / RBLK;
  int m0 = b * chunk, m1 = min(MPC, m0 + chunk);
  for (int m = m0 + tid; m < m1; m += 256) atomicAdd(&h[rs[m]], 1);
  __syncthreads();
  for (int i = tid; i < NR2; i += 256) blkcnt[((size_t)(t * RBLK + b)) * NR2 + i] = h[i];
}

// a) per-(t,rel) totals
__global__ __launch_bounds__(256) void k_scanR2a(const int* __restrict__ blkcnt,
                                                 int* __restrict__ tot) {
  int idx = blockIdx.x * 256 + threadIdx.x;
  if (idx >= TS * NR2) return;
  int t = idx / NR2, r = idx - t * NR2;
  int s = 0;
  for (int b = 0; b < RBLK; ++b) s += blkcnt[((size_t)(t * RBLK + b)) * NR2 + r];
  tot[idx] = s;
}

// b) tiny serial per-step scan -> offsR + invc
__global__ __launch_bounds__(512) void k_scanR2b(const int* __restrict__ tot,
    int* __restrict__ offsR, float* __restrict__ invc) {
  __shared__ int s[TS * NR2];
  int tid = threadIdx.x;
  for (int i = tid; i < TS * NR2; i += 512) s[i] = tot[i];
  __syncthreads();
  if (tid < TS) {
    int acc = tid * MPC;
    for (int r = 0; r < NR2; ++r) { int c = s[tid * NR2 + r]; s[tid * NR2 + r] = acc; acc += c; }
  }
  __syncthreads();
  for (int i = tid; i < TS * NR2; i += 512) {
    offsR[i] = s[i];
    int c = tot[i];
    invc[i] = c > 0 ? 1.0f / (float)c : 0.0f;
  }
  if (tid == 0) offsR[TS * NR2] = TS * MPC;
}

// c) one wave per (t,rel): prefix over RBLK block-counts -> per-block bases
__global__ __launch_bounds__(256) void k_scanR2c(int* __restrict__ blkcnt,
                                                 const int* __restrict__ offsR) {
  int gw = (blockIdx.x * blockDim.x + threadIdx.x) >> 6;
  int lane = threadIdx.x & 63;
  if (gw >= TS * NR2) return;
  int t = gw / NR2, r = gw - t * NR2;
  size_t i0 = ((size_t)(t * RBLK + lane * 2)) * NR2 + r;
  size_t i1 = ((size_t)(t * RBLK + lane * 2 + 1)) * NR2 + r;
  int v0 = blkcnt[i0], v1 = blkcnt[i1];
  int s = v0 + v1;
  int sc = s;
  #pragma unroll
  for (int o = 1; o < 64; o <<= 1) {
    int x = __shfl_up(sc, o, 64);
    if (lane >= o) sc += x;
  }
  int basev = offsR[gw] + (sc - s);
  blkcnt[i0] = basev;
  blkcnt[i1] = basev + v0;
}

__global__ __launch_bounds__(256) void k_scatterR2(const int* __restrict__ rte,
    const int* __restrict__ rseg, const int* __restrict__ blkbase,
    int* __restrict__ out) {
  __shared__ int cur[NR2];
  int b = blockIdx.x, t = blockIdx.y, tid = threadIdx.x;
  for (int i = tid; i < NR2; i += 256) cur[i] = blkbase[((size_t)(t * RBLK + b)) * NR2 + i];
  __syncthreads();
  const int* rs = rseg + (size_t)t * MPC;
  const int* re = rte + (size_t)t * MPC;
  int chunk = (MPC + RBLK - 1) / RBLK;
  int m0 = b * chunk, m1 = min(MPC, m0 + chunk);
  for (int m = m0 + tid; m < m1; m += 256) {
    int r = rs[m];
    int p = atomicAdd(&cur[r], 1);
    out[p] = re[m];
  }
}

// ---- flat 3-phase exclusive scan over TS*NENT degrees ----
__global__ __launch_bounds__(256) void k_scan1(const int* __restrict__ deg,
    int* __restrict__ offs, float* __restrict__ normv, int* __restrict__ bsum) {
  __shared__ int sd[256];
  int b = blockIdx.x, tid = threadIdx.x;
  int i = b * 256 + tid;
  int v = (i < NTOT) ? deg[i] : 0;
  sd[tid] = v;
  __syncthreads();
  for (int o = 1; o < 256; o <<= 1) {
    int x = (tid >= o) ? sd[tid - o] : 0;
    __syncthreads();
    sd[tid] += x;
    __syncthreads();
  }
  if (i < NTOT) {
    offs[i] = sd[tid] - v;
    normv[i] = v > 0 ? 1.0f / (float)v : 0.0f;
  }
  if (tid == 255) bsum[b] = sd[255];
}

__global__ __launch_bounds__(256) void k_scan2(int* __restrict__ bsum) {
  __shared__ int part[256];
  int tid = threadIdx.x;
  int base = tid * SCAN2_PER;
  int local[SCAN2_PER];
  int s = 0;
  #pragma unroll
  for (int k = 0; k < SCAN2_PER; ++k) {
    int v = (base + k < NB8) ? bsum[base + k] : 0;
    local[k] = s;
    s += v;
  }
  part[tid] = s;
  __syncthreads();
  for (int o = 1; o < 256; o <<= 1) {
    int x = (tid >= o) ? part[tid - o] : 0;
    __syncthreads();
    part[tid] += x;
    __syncthreads();
  }
  int pre = (tid > 0) ? part[tid - 1] : 0;
  #pragma unroll
  for (int k = 0; k < SCAN2_PER; ++k)
    if (base + k < NB8) bsum[base + k] = pre + local[k];
}

__global__ __launch_bounds__(256) void k_scan3(int* __restrict__ offs, int* __restrict__ cur,
                                               const int* __restrict__ bsum) {
  int b = blockIdx.x;
  int i = b * 256 + threadIdx.x;
  if (i < NTOT) {
    int o = offs[i] + bsum[b];
    offs[i] = o;
    cur[i] = o;
  }
  if (b == 0 && threadIdx.x == 0) offs[NTOT] = TS * EPC;
}

__global__ void k_scatterE(const int* __restrict__ src, const int* __restrict__ dst,
                           const int* __restrict__ ety, int* __restrict__ cur,
                           int2* __restrict__ se) {
  int i = blockIdx.x * blockDim.x + threadIdx.x;
  int gs = gridDim.x * blockDim.x;
  for (; i < TS * EPC; i += gs) {
    int t = i / EPC;
    int d = dst[i];
    int p = atomicAdd(&cur[t * NENT + d], 1);
    se[p] = make_int2(src[i], ety[i]);
  }
}

// ---- W -> fragment-layout bf16 hi/lo (B-operand of mfma_f32_16x16x32_bf16) ----
// frag element j of (nt, ks, lane): B[k = ks*32 + (lane>>4)*8 + j][n = nt*16 + (lane&15)]
__global__ __launch_bounds__(256) void k_prepW(const float* __restrict__ W,
    unsigned short* __restrict__ hi, unsigned short* __restrict__ lo) {
  int t = blockIdx.x * 256 + threadIdx.x;   // 0..2047
  int nt = t >> 8, ks = (t >> 6) & 3, lane = t & 63;
  int n = nt * 16 + (lane & 15);
  int k0 = ks * 32 + ((lane >> 4) << 3);
  #pragma unroll
  for (int j = 0; j < 8; ++j) {
    float v = W[(k0 + j) * HD + n];
    unsigned short h = f2bf_rne(v);
    hi[t * 8 + j] = h;
    lo[t * 8 + j] = f2bf_rne(v - bf2f(h));
  }
}

// ---- relation partial sums via CSR gather ----
__global__ __launch_bounds__(256) void k_relmean(const float* __restrict__ h,
    const int* __restrict__ offs, const int* __restrict__ rte_csr,
    float* __restrict__ partials) {
  int rel = blockIdx.x, sp = blockIdx.y;
  int o0 = offs[rel], o1 = offs[rel + 1];
  int n = o1 - o0;
  int s0 = o0 + ((n * sp) >> 3);
  int s1 = o0 + ((n * (sp + 1)) >> 3);
  int w = threadIdx.x >> 6, lane = threadIdx.x & 63;
  const float2* h2 = (const float2*)h;
  float sx = 0.f, sy = 0.f;
  int p = s0 + w;
  for (; p + 4 < s1; p += 8) {
    int i0 = rte_csr[p];
    int i1 = rte_csr[p + 4];
    float2 v0 = h2[(size_t)i0 * 64 + lane];
    float2 v1 = h2[(size_t)i1 * 64 + lane];
    sx += v0.x + v1.x; sy += v0.y + v1.y;
  }
  for (; p < s1; p += 4) {
    int i0 = rte_csr[p];
    float2 v0 = h2[(size_t)i0 * 64 + lane];
    sx += v0.x; sy += v0.y;
  }
  __shared__ float red[4][HD];
  red[w][lane * 2] = sx;
  red[w][lane * 2 + 1] = sy;
  __syncthreads();
  if (threadIdx.x < HD) {
    int j = threadIdx.x;
    float t = red[0][j] + red[1][j] + red[2][j] + red[3][j];
    partials[((size_t)sp * NR2 + rel) * HD + j] = t;
  }
}

// ---- GRU cell + l2norm for 460 relation rows ----
__global__ __launch_bounds__(HD) void k_gru(
    const float* __restrict__ partials, const float* __restrict__ invcnt,
    const float* __restrict__ emb_rel, const float* __restrict__ h0s,
    const float* __restrict__ Wih, const float* __restrict__ Whh,
    const float* __restrict__ bih, const float* __restrict__ bhh,
    float* __restrict__ h0d) {
  int r = blockIdx.x, j = threadIdx.x;
  __shared__ __align__(16) float xr[2 * HD];
  __shared__ __align__(16) float hh[HD];
  __shared__ float red[HD];
  float inv = invcnt[r];
  xr[j] = emb_rel[r * HD + j];
  float xm = 0.f;
  #pragma unroll
  for (int sp = 0; sp < RSP; ++sp) xm += partials[((size_t)sp * NR2 + r) * HD + j];
  xr[HD + j] = xm * inv;
  float hv0 = h0s[r * HD + j];
  hh[j] = hv0;
  __syncthreads();
  float gr = bih[j], gz = bih[HD + j], gn = bih[2 * HD + j];
  const float4* W4 = (const float4*)Wih;
  int rowA = j * 64, rowB = (j + HD) * 64, rowC = (j + 2 * HD) * 64;
  #pragma unroll 4
  for (int k4 = 0; k4 < 64; ++k4) {
    float4 xa = ((const float4*)xr)[k4];
    float4 w0 = W4[rowA + k4];
    float4 w1 = W4[rowB + k4];
    float4 w2 = W4[rowC + k4];
    gr += w0.x * xa.x + w0.y * xa.y + w0.z * xa.z + w0.w * xa.w;
    gz += w1.x * xa.x + w1.y * xa.y + w1.z * xa.z + w1.w * xa.w;
    gn += w2.x * xa.x + w2.y * xa.y + w2.z * xa.z + w2.w * xa.w;
  }
  float hr = bhh[j], hz = bhh[HD + j], hn = bhh[2 * HD + j];
  const float4* Wh4 = (const float4*)Whh;
  int rA = j * 32, rB = (j + HD) * 32, rC = (j + 2 * HD) * 32;
  #pragma unroll 4
  for (int k4 = 0; k4 < 32; ++k4) {
    float4 xa = ((const float4*)hh)[k4];
    float4 w0 = Wh4[rA + k4];
    float4 w1 = Wh4[rB + k4];
    float4 w2 = Wh4[rC + k4];
    hr += w0.x * xa.x + w0.y * xa.y + w0.z * xa.z + w0.w * xa.w;
    hz += w1.x * xa.x + w1.y * xa.y + w1.z * xa.z + w1.w * xa.w;
    hn += w2.x * xa.x + w2.y * xa.y + w2.z * xa.z + w2.w * xa.w;
  }
  float rg = sigm(gr + hr);
  float zg = sigm(gz + hz);
  float ng = tanhf(gn + rg * hn);
  float hv = (1.0f - zg) * ng + zg * hv0;
  red[j] = hv * hv;
  __syncthreads();
  for (int s = HD / 2; s > 0; s >>= 1) { if (j < s) red[j] += red[j + s]; __syncthreads(); }
  float rn = 1.0f / fmaxf(sqrtf(red[0]), 1e-12f);
  h0d[r * HD + j] = hv * rn;
}

// ---- edge aggregation via dst-CSR ----
__global__ __launch_bounds__(256) void k_edge_csr(
    const float* __restrict__ nh, const float* __restrict__ h0,
    const int* __restrict__ offs, const int2* __restrict__ se,
    const float* __restrict__ norm, float* __restrict__ agg) {
  int gw = (blockIdx.x * blockDim.x + threadIdx.x) >> 6;
  int lane = threadIdx.x & 63;
  if (gw >= NENT) return;
  int o0 = offs[gw], o1 = offs[gw + 1];
  const float2* nh2 = (const float2*)nh;
  const float2* h02 = (const float2*)h0;
  float sx = 0.f, sy = 0.f;
  int p = o0;
  for (; p + 2 <= o1; p += 2) {
    int2 a = se[p];
    int2 b = se[p + 1];
    float2 va = nh2[(size_t)a.x * 64 + lane];
    float2 ra = h02[(size_t)a.y * 64 + lane];
    float2 vb = nh2[(size_t)b.x * 64 + lane];
    float2 rb = h02[(size_t)b.y * 64 + lane];
    sx += (va.x + ra.x) + (vb.x + rb.x);
    sy += (va.y + ra.y) + (vb.y + rb.y);
  }
  if (p < o1) {
    int2 a = se[p];
    float2 va = nh2[(size_t)a.x * 64 + lane];
    float2 ra = h02[(size_t)a.y * 64 + lane];
    sx += va.x + ra.x;
    sy += va.y + ra.y;
  }
  float nm = norm[gw];
  ((float2*)agg)[(size_t)gw * 64 + lane] = make_float2(sx * nm, sy * nm);
}

// ---- MFMA split-bf16 in-place A = rrelu(A @ W) ----
__global__ __launch_bounds__(256) void k_mm_mfma(
    float* __restrict__ A, const unsigned short* __restrict__ wHi,
    const unsigned short* __restrict__ wLo, int nrows) {
  __shared__ __align__(16) unsigned short AsH[64 * 128];
  __shared__ __align__(16) unsigned short AsL[64 * 128];
  int tid = threadIdx.x;
  int base = blockIdx.x * 64;
  const float4* A4 = (const float4*)A;
  #pragma unroll
  for (int it = 0; it < 8; ++it) {
    int idx = tid + it * 256;          // 0..2047
    int r = idx >> 5, c4 = idx & 31;
    int c0 = c4 * 4;
    float4 v = make_float4(0.f, 0.f, 0.f, 0.f);
    if (base + r < nrows) v = A4[(size_t)(base + r) * 32 + c4];
    int chunk = (c0 >> 3) ^ (r & 7);
    int p = r * 128 + chunk * 8 + (c0 & 7);
    unsigned short h0 = f2bf_rne(v.x), h1 = f2bf_rne(v.y);
    unsigned short h2 = f2bf_rne(v.z), h3 = f2bf_rne(v.w);
    ushort4 hv; hv.x = h0; hv.y = h1; hv.z = h2; hv.w = h3;
    *(ushort4*)&AsH[p] = hv;
    ushort4 lv;
    lv.x = f2bf_rne(v.x - bf2f(h0)); lv.y = f2bf_rne(v.y - bf2f(h1));
    lv.z = f2bf_rne(v.z - bf2f(h2)); lv.w = f2bf_rne(v.w - bf2f(h3));
    *(ushort4*)&AsL[p] = lv;
  }
  __syncthreads();
  int w = tid >> 6, lane = tid & 63;
  int lrow = lane & 15, lk = lane >> 4;
  facc acc[8];
  #pragma unroll
  for (int nt = 0; nt < 8; ++nt) acc[nt] = (facc){0.f, 0.f, 0.f, 0.f};
  int arow = w * 16 + lrow;
  #pragma unroll
  for (int ks = 0; ks < 4; ++ks) {
    int chunk = (ks * 4 + lk) ^ (arow & 7);
    int p = arow * 128 + chunk * 8;
    bfrag aH = *(const bfrag*)&AsH[p];
    bfrag aL = *(const bfrag*)&AsL[p];
    #pragma unroll
    for (int nt = 0; nt < 8; ++nt) {
      int fi = ((nt * 4 + ks) * 64 + lane) * 8;
      bfrag bH = *(const bfrag*)&wHi[fi];
      bfrag bL = *(const bfrag*)&wLo[fi];
      acc[nt] = __builtin_amdgcn_mfma_f32_16x16x32_bf16(aH, bH, acc[nt], 0, 0, 0);
      acc[nt] = __builtin_amdgcn_mfma_f32_16x16x32_bf16(aH, bL, acc[nt], 0, 0, 0);
      acc[nt] = __builtin_amdgcn_mfma_f32_16x16x32_bf16(aL, bH, acc[nt], 0, 0, 0);
    }
  }
  #pragma unroll
  for (int nt = 0; nt < 8; ++nt)
    #pragma unroll
    for (int r = 0; r < 4; ++r) {
      int row = base + w * 16 + lk * 4 + r;
      if (row < nrows) A[(size_t)row * HD + nt * 16 + lrow] = rrelu_f(acc[nt][r]);
    }
}

// ---- MFMA split-bf16 fused final: tw = sigm(Hin@Wt + b); out = tw*l2norm(C) + (1-tw)*Hin ----
__global__ __launch_bounds__(256) void k_final_mfma(
    const float* __restrict__ C, const float* __restrict__ Hin, float* __restrict__ Hout,
    const unsigned short* __restrict__ wHi, const unsigned short* __restrict__ wLo,
    const float* __restrict__ bias, int nrows) {
  __shared__ __align__(16) unsigned short AsH[64 * 128];
  __shared__ __align__(16) unsigned short AsL[64 * 128];
  int tid = threadIdx.x;
  int base = blockIdx.x * 64;
  const float4* H4 = (const float4*)Hin;
  #pragma unroll
  for (int it = 0; it < 8; ++it) {
    int idx = tid + it * 256;
    int r = idx >> 5, c4 = idx & 31;
    int c0 = c4 * 4;
    float4 v = make_float4(0.f, 0.f, 0.f, 0.f);
    if (base + r < nrows) v = H4[(size_t)(base + r) * 32 + c4];
    int chunk = (c0 >> 3) ^ (r & 7);
    int p = r * 128 + chunk * 8 + (c0 & 7);
    unsigned short h0 = f2bf_rne(v.x), h1 = f2bf_rne(v.y);
    unsigned short h2 = f2bf_rne(v.z), h3 = f2bf_rne(v.w);
    ushort4 hv; hv.x = h0; hv.y = h1; hv.z = h2; hv.w = h3;
    *(ushort4*)&AsH[p] = hv;
    ushort4 lv;
    lv.x = f2bf_rne(v.x - bf2f(h0)); lv.y = f2bf_rne(v.y - bf2f(h1));
    lv.z = f2bf_rne(v.z - bf2f(h2)); lv.w = f2bf_rne(v.w - bf2f(h3));
    *(ushort4*)&AsL[p] = lv;
  }
  __syncthreads();
  int w = tid >> 6, lane = tid & 63;
  int lrow = lane & 15, lk = lane >> 4;
  facc acc[8];
  #pragma unroll
  for (int nt = 0; nt < 8; ++nt) acc[nt] = (facc){0.f, 0.f, 0.f, 0.f};
  int arow = w * 16 + lrow;
  #pragma unroll
  for (int ks = 0; ks < 4; ++ks) {
    int chunk = (ks * 4 + lk) ^ (arow & 7);
    int p = arow * 128 + chunk * 8;
    bfrag aH = *(const bfrag*)&AsH[p];
    bfrag aL = *(const bfrag*)&AsL[p];
    #pragma unroll
    for (int nt = 0; nt < 8; ++nt) {
      int fi = ((nt * 4 + ks) * 64 + lane) * 8;
      bfrag bH = *(const bfrag*)&wHi[fi];
      bfrag bL = *(const bfrag*)&wLo[fi];
      acc[nt] = __builtin_amdgcn_mfma_f32_16x16x32_bf16(aH, bH, acc[nt], 0, 0, 0);
      acc[nt] = __builtin_amdgcn_mfma_f32_16x16x32_bf16(aH, bL, acc[nt], 0, 0, 0);
      acc[nt] = __builtin_amdgcn_mfma_f32_16x16x32_bf16(aL, bH, acc[nt], 0, 0, 0);
    }
  }
  // epilogue: lane covers rows (w*16 + lk*4 + r), cols (nt*16 + lrow)
  float cv[8][4];
  float ss[4] = {0.f, 0.f, 0.f, 0.f};
  #pragma unroll
  for (int r = 0; r < 4; ++r) {
    int row = base + w * 16 + lk * 4 + r;
    int rok = row < nrows;
    #pragma unroll
    for (int nt = 0; nt < 8; ++nt) {
      float x = rok ? C[(size_t)row * HD + nt * 16 + lrow] : 0.f;
      cv[nt][r] = x;
      ss[r] += x * x;
    }
  }
  #pragma unroll
  for (int r = 0; r < 4; ++r) {
    #pragma unroll
    for (int o = 1; o < 16; o <<= 1) ss[r] += __shfl_xor(ss[r], o, 64);
    ss[r] = 1.0f / fmaxf(sqrtf(ss[r]), 1e-12f);
  }
  #pragma unroll
  for (int r = 0; r < 4; ++r) {
    int row = base + w * 16 + lk * 4 + r;
    if (row >= nrows) continue;
    #pragma unroll
    for (int nt = 0; nt < 8; ++nt) {
      int col = nt * 16 + lrow;
      float hv = Hin[(size_t)row * HD + col];
      float tw = sigm(acc[nt][r] + bias[col]);
      Hout[(size_t)row * HD + col] = tw * (cv[nt][r] * ss[r]) + (1.0f - tw) * hv;
    }
  }
}

extern "C" void kernel_launch(void* const* d_in, const int* in_sizes, int n_in,
                              void* d_out, int out_size, void* d_ws, size_t ws_size,
                              hipStream_t stream) {
  const int* src    = (const int*)d_in[0];
  const int* dst    = (const int*)d_in[1];
  const int* etype  = (const int*)d_in[2];
  const int* rte    = (const int*)d_in[3];
  const int* rseg   = (const int*)d_in[4];
  const float* dyn  = (const float*)d_in[5];
  const float* emb_rel = (const float*)d_in[6];
  const float* W_ih = (const float*)d_in[7];
  const float* W_hh = (const float*)d_in[8];
  const float* b_ih = (const float*)d_in[9];
  const float* b_hh = (const float*)d_in[10];
  const float* rgcnW = (const float*)d_in[11];
  const float* tgW  = (const float*)d_in[12];
  const float* tgB  = (const float*)d_in[13];
  float* out = (float*)d_out;
  (void)in_sizes; (void)n_in; (void)out_size; (void)ws_size;

  float* ws = (float*)d_ws;
  size_t off = 0;
  float* agg1    = ws + off; off += (size_t)NENT * HD;
  float* agg2    = ws + off; off += (size_t)NENT * HD;
  float* parts   = ws + off; off += (size_t)RSP * NR2 * HD;
  float* h0a     = ws + off; off += (size_t)NR2 * HD;
  float* h0b     = ws + off; off += (size_t)NR2 * HD;
  float* normv8  = ws + off; off += NTOT;
  float* invc8   = ws + off; off += TS * NR2;
  off = (off + 3) & ~(size_t)3;   // 16B alignment
  unsigned short* wf = (unsigned short*)(ws + off);
  // 6 fragment buffers (W1 hi/lo, W2 hi/lo, Wt hi/lo), each 16384 ushorts
  unsigned short* w1H = wf;            unsigned short* w1L = wf + 16384;
  unsigned short* w2H = wf + 32768;    unsigned short* w2L = wf + 49152;
  unsigned short* wtH = wf + 65536;    unsigned short* wtL = wf + 81920;
  off += (6 * 16384) / 2;
  off = (off + 1) & ~(size_t)1;   // 8B alignment for int2
  int2* csr_se8  = (int2*)(ws + off); off += (size_t)2 * TS * EPC;
  int* csr_rte8  = (int*)(ws + off);  off += (size_t)TS * MPC;
  int* degE8     = (int*)(ws + off);  off += NTOT;
  int* offsE8    = (int*)(ws + off);  off += NTOT + 2;
  int* curE8     = (int*)(ws + off);  off += NTOT;
  int* bsum      = (int*)(ws + off);  off += NB8;
  int* blkcntR8  = (int*)(ws + off);  off += (size_t)TS * RBLK * NR2;
  int* offsR8    = (int*)(ws + off);  off += TS * NR2 + 2;
  int* totR      = (int*)(ws + off);  off += TS * NR2;

  // ===== hoisted, batched CSR builds for all TS steps (input-only) =====
  hipMemsetAsync(degE8, 0, (size_t)NTOT * sizeof(int), stream);
  k_hist<<<2048, 256, 0, stream>>>(dst, degE8, TS * EPC, EPC, NENT);
  k_scan1<<<NB8, 256, 0, stream>>>(degE8, offsE8, normv8, bsum);
  k_scan2<<<1, 256, 0, stream>>>(bsum);
  k_scan3<<<NB8, 256, 0, stream>>>(offsE8, curE8, bsum);
  k_scatterE<<<2048, 256, 0, stream>>>(src, dst, etype, curE8, csr_se8);
  k_histR2<<<dim3(RBLK, TS), 256, 0, stream>>>(rseg, blkcntR8);
  k_scanR2a<<<(TS * NR2 + 255) / 256, 256, 0, stream>>>(blkcntR8, totR);
  k_scanR2b<<<1, 512, 0, stream>>>(totR, offsR8, invc8);
  k_scanR2c<<<(TS * NR2 * 64 + 255) / 256, 256, 0, stream>>>(blkcntR8, offsR8);
  k_scatterR2<<<dim3(RBLK, TS), 256, 0, stream>>>(rte, rseg, blkcntR8, csr_rte8);
  // W fragment prep (bf16 hi/lo)
  k_prepW<<<8, 256, 0, stream>>>(rgcnW, w1H, w1L);
  k_prepW<<<8, 256, 0, stream>>>(rgcnW + HD * HD, w2H, w2L);
  k_prepW<<<8, 256, 0, stream>>>(tgW, wtH, wtL);

  // h_init = l2norm(dynamic_emb) -> d_out slot 0 doubles as first h
  k_l2rows<<<NENT, HD, 0, stream>>>(dyn, out);

  float* h0bufs[2] = {h0a, h0b};
  for (int t = 0; t < TS; ++t) {
    const float* h = out + (size_t)(t == 0 ? 0 : (t - 1)) * NENT * HD;
    float* hout = out + (size_t)t * NENT * HD;
    const float* h0s = (t == 0) ? emb_rel : h0bufs[(t - 1) & 1];
    float* h0d = h0bufs[t & 1];

    k_relmean<<<dim3(NR2, RSP), 256, 0, stream>>>(h, offsR8 + t * NR2, csr_rte8, parts);
    k_gru<<<NR2, HD, 0, stream>>>(parts, invc8 + t * NR2, emb_rel, h0s,
                                  W_ih, W_hh, b_ih, b_hh, h0d);

    k_edge_csr<<<(NENT * 64 + 255) / 256, 256, 0, stream>>>(
        h, h0d, offsE8 + t * NENT, csr_se8, normv8 + t * NENT, agg1);
    k_mm_mfma<<<(NENT + 63) / 64, 256, 0, stream>>>(agg1, w1H, w1L, NENT);
    k_edge_csr<<<(NENT * 64 + 255) / 256, 256, 0, stream>>>(
        agg1, h0d, offsE8 + t * NENT, csr_se8, normv8 + t * NENT, agg2);
    k_mm_mfma<<<(NENT + 63) / 64, 256, 0, stream>>>(agg2, w2H, w2L, NENT);

    k_final_mfma<<<(NENT + 63) / 64, 256, 0, stream>>>(agg2, h, hout, wtH, wtL, tgB, NENT);
  }
  hipMemcpyAsync(out + (size_t)TS * NENT * HD, h0bufs[(TS - 1) & 1],
                 (size_t)NR2 * HD * sizeof(float), hipMemcpyDeviceToDevice, stream);
}

// Round 6
// 1690.359 us; speedup vs baseline: 6.4747x; 1.0566x over previous
//
#include <hip/hip_runtime.h>
#include <math.h>

#define NENT 50000
#define NR2 460
#define HD 128
#define TS 8
#define EPC 200000   // edges per step
#define MPC 400000   // r_to_e entries per step
#define RSLOPE 0.22916666666666666f
#define RBLK 128                    // blocks per step for two-level relation CSR build
#define NTOT (TS * NENT)            // 400000 flattened (t, entity)
#define NB8 ((NTOT + 255) / 256)    // 1563 scan blocks
#define SCAN2_PER ((NB8 + 255) / 256)  // 7
#define RSP 8                       // relmean splits

typedef __attribute__((ext_vector_type(8))) short bfrag;   // 8 bf16 (4 VGPR)
typedef __attribute__((ext_vector_type(4))) float facc;    // mfma f32x4 acc

__device__ __forceinline__ float sigm(float x) { return 1.0f / (1.0f + expf(-x)); }
__device__ __forceinline__ float rrelu_f(float x) { return x >= 0.0f ? x : RSLOPE * x; }
__device__ __forceinline__ unsigned short f2bf_rne(float x) {
  unsigned u = __float_as_uint(x);
  unsigned r = (u + 0x7FFFu + ((u >> 16) & 1u)) >> 16;
  return (unsigned short)r;
}
__device__ __forceinline__ float bf2f(unsigned short b) {
  return __uint_as_float(((unsigned)b) << 16);
}
__device__ __forceinline__ float bfLO(unsigned u) { return __uint_as_float(u << 16); }
__device__ __forceinline__ float bfHI(unsigned u) { return __uint_as_float(u & 0xFFFF0000u); }

// ---- row l2 normalize (+ bf16 shadow) ----
__global__ __launch_bounds__(HD) void k_l2rows(const float* __restrict__ in,
                                               float* __restrict__ out,
                                               unsigned short* __restrict__ out_bf) {
  int r = blockIdx.x, j = threadIdx.x;
  __shared__ float red[HD];
  float v = in[(size_t)r * HD + j];
  red[j] = v * v;
  __syncthreads();
  for (int s = HD / 2; s > 0; s >>= 1) { if (j < s) red[j] += red[j + s]; __syncthreads(); }
  float rn = 1.0f / fmaxf(sqrtf(red[0]), 1e-12f);
  float o = v * rn;
  out[(size_t)r * HD + j] = o;
  out_bf[(size_t)r * HD + j] = f2bf_rne(o);
}

// ---- batched histogram ----
__global__ void k_hist(const int* __restrict__ idx, int* __restrict__ cnt,
                       int n, int per_t, int stride) {
  int i = blockIdx.x * blockDim.x + threadIdx.x;
  int gs = gridDim.x * blockDim.x;
  for (; i < n; i += gs) atomicAdd(&cnt[(i / per_t) * stride + idx[i]], 1);
}

// ==== batched two-level relation CSR build ====
__global__ __launch_bounds__(256) void k_histR2(const int* __restrict__ rseg,
                                                int* __restrict__ blkcnt) {
  __shared__ int h[NR2];
  int b = blockIdx.x, t = blockIdx.y, tid = threadIdx.x;
  for (int i = tid; i < NR2; i += 256) h[i] = 0;
  __syncthreads();
  const int* rs = rseg + (size_t)t * MPC;
  int chunk = (MPC + RBLK - 1) / RBLK;
  int m0 = b * chunk, m1 = min(MPC, m0 + chunk);
  for (int m = m0 + tid; m < m1; m += 256) atomicAdd(&h[rs[m]], 1);
  __syncthreads();
  for (int i = tid; i < NR2; i += 256) blkcnt[((size_t)(t * RBLK + b)) * NR2 + i] = h[i];
}

__global__ __launch_bounds__(256) void k_scanR2a(const int* __restrict__ blkcnt,
                                                 int* __restrict__ tot) {
  int idx = blockIdx.x * 256 + threadIdx.x;
  if (idx >= TS * NR2) return;
  int t = idx / NR2, r = idx - t * NR2;
  int s = 0;
  for (int b = 0; b < RBLK; ++b) s += blkcnt[((size_t)(t * RBLK + b)) * NR2 + r];
  tot[idx] = s;
}

__global__ __launch_bounds__(512) void k_scanR2b(const int* __restrict__ tot,
    int* __restrict__ offsR, float* __restrict__ invc) {
  __shared__ int s[TS * NR2];
  int tid = threadIdx.x;
  for (int i = tid; i < TS * NR2; i += 512) s[i] = tot[i];
  __syncthreads();
  if (tid < TS) {
    int acc = tid * MPC;
    for (int r = 0; r < NR2; ++r) { int c = s[tid * NR2 + r]; s[tid * NR2 + r] = acc; acc += c; }
  }
  __syncthreads();
  for (int i = tid; i < TS * NR2; i += 512) {
    offsR[i] = s[i];
    int c = tot[i];
    invc[i] = c > 0 ? 1.0f / (float)c : 0.0f;
  }
  if (tid == 0) offsR[TS * NR2] = TS * MPC;
}

__global__ __launch_bounds__(256) void k_scanR2c(int* __restrict__ blkcnt,
                                                 const int* __restrict__ offsR) {
  int gw = (blockIdx.x * blockDim.x + threadIdx.x) >> 6;
  int lane = threadIdx.x & 63;
  if (gw >= TS * NR2) return;
  int t = gw / NR2, r = gw - t * NR2;
  size_t i0 = ((size_t)(t * RBLK + lane * 2)) * NR2 + r;
  size_t i1 = ((size_t)(t * RBLK + lane * 2 + 1)) * NR2 + r;
  int v0 = blkcnt[i0], v1 = blkcnt[i1];
  int s = v0 + v1;
  int sc = s;
  #pragma unroll
  for (int o = 1; o < 64; o <<= 1) {
    int x = __shfl_up(sc, o, 64);
    if (lane >= o) sc += x;
  }
  int basev = offsR[gw] + (sc - s);
  blkcnt[i0] = basev;
  blkcnt[i1] = basev + v0;
}

__global__ __launch_bounds__(256) void k_scatterR2(const int* __restrict__ rte,
    const int* __restrict__ rseg, const int* __restrict__ blkbase,
    int* __restrict__ out) {
  __shared__ int cur[NR2];
  int b = blockIdx.x, t = blockIdx.y, tid = threadIdx.x;
  for (int i = tid; i < NR2; i += 256) cur[i] = blkbase[((size_t)(t * RBLK + b)) * NR2 + i];
  __syncthreads();
  const int* rs = rseg + (size_t)t * MPC;
  const int* re = rte + (size_t)t * MPC;
  int chunk = (MPC + RBLK - 1) / RBLK;
  int m0 = b * chunk, m1 = min(MPC, m0 + chunk);
  for (int m = m0 + tid; m < m1; m += 256) {
    int r = rs[m];
    int p = atomicAdd(&cur[r], 1);
    out[p] = re[m];
  }
}

// ---- flat 3-phase exclusive scan over TS*NENT degrees ----
__global__ __launch_bounds__(256) void k_scan1(const int* __restrict__ deg,
    int* __restrict__ offs, float* __restrict__ normv, int* __restrict__ bsum) {
  __shared__ int sd[256];
  int b = blockIdx.x, tid = threadIdx.x;
  int i = b * 256 + tid;
  int v = (i < NTOT) ? deg[i] : 0;
  sd[tid] = v;
  __syncthreads();
  for (int o = 1; o < 256; o <<= 1) {
    int x = (tid >= o) ? sd[tid - o] : 0;
    __syncthreads();
    sd[tid] += x;
    __syncthreads();
  }
  if (i < NTOT) {
    offs[i] = sd[tid] - v;
    normv[i] = v > 0 ? 1.0f / (float)v : 0.0f;
  }
  if (tid == 255) bsum[b] = sd[255];
}

__global__ __launch_bounds__(256) void k_scan2(int* __restrict__ bsum) {
  __shared__ int part[256];
  int tid = threadIdx.x;
  int base = tid * SCAN2_PER;
  int local[SCAN2_PER];
  int s = 0;
  #pragma unroll
  for (int k = 0; k < SCAN2_PER; ++k) {
    int v = (base + k < NB8) ? bsum[base + k] : 0;
    local[k] = s;
    s += v;
  }
  part[tid] = s;
  __syncthreads();
  for (int o = 1; o < 256; o <<= 1) {
    int x = (tid >= o) ? part[tid - o] : 0;
    __syncthreads();
    part[tid] += x;
    __syncthreads();
  }
  int pre = (tid > 0) ? part[tid - 1] : 0;
  #pragma unroll
  for (int k = 0; k < SCAN2_PER; ++k)
    if (base + k < NB8) bsum[base + k] = pre + local[k];
}

__global__ __launch_bounds__(256) void k_scan3(int* __restrict__ offs, int* __restrict__ cur,
                                               const int* __restrict__ bsum) {
  int b = blockIdx.x;
  int i = b * 256 + threadIdx.x;
  if (i < NTOT) {
    int o = offs[i] + bsum[b];
    offs[i] = o;
    cur[i] = o;
  }
  if (b == 0 && threadIdx.x == 0) offs[NTOT] = TS * EPC;
}

// packed edge payload: (src << 9) | etype   (src < 2^17, etype < 512)
__global__ void k_scatterE(const int* __restrict__ src, const int* __restrict__ dst,
                           const int* __restrict__ ety, int* __restrict__ cur,
                           unsigned* __restrict__ se) {
  int i = blockIdx.x * blockDim.x + threadIdx.x;
  int gs = gridDim.x * blockDim.x;
  for (; i < TS * EPC; i += gs) {
    int t = i / EPC;
    int d = dst[i];
    int p = atomicAdd(&cur[t * NENT + d], 1);
    se[p] = ((unsigned)src[i] << 9) | (unsigned)ety[i];
  }
}

// ---- W -> fragment-layout bf16 hi/lo (B-operand of mfma_f32_16x16x32_bf16) ----
__global__ __launch_bounds__(256) void k_prepW(const float* __restrict__ W,
    unsigned short* __restrict__ hi, unsigned short* __restrict__ lo) {
  int t = blockIdx.x * 256 + threadIdx.x;   // 0..2047
  int nt = t >> 8, ks = (t >> 6) & 3, lane = t & 63;
  int n = nt * 16 + (lane & 15);
  int k0 = ks * 32 + ((lane >> 4) << 3);
  #pragma unroll
  for (int j = 0; j < 8; ++j) {
    float v = W[(k0 + j) * HD + n];
    unsigned short h = f2bf_rne(v);
    hi[t * 8 + j] = h;
    lo[t * 8 + j] = f2bf_rne(v - bf2f(h));
  }
}

// ---- relation partial sums via CSR gather (bf16 rows) ----
__global__ __launch_bounds__(256) void k_relmean(const unsigned short* __restrict__ h_bf,
    const int* __restrict__ offs, const int* __restrict__ rte_csr,
    float* __restrict__ partials) {
  int rel = blockIdx.x, sp = blockIdx.y;
  int o0 = offs[rel], o1 = offs[rel + 1];
  int n = o1 - o0;
  int s0 = o0 + ((n * sp) >> 3);
  int s1 = o0 + ((n * (sp + 1)) >> 3);
  int w = threadIdx.x >> 6, lane = threadIdx.x & 63;
  const unsigned* h4 = (const unsigned*)h_bf;   // 2 bf16 per u32; row = idx*64 u32
  float sx = 0.f, sy = 0.f;
  int p = s0 + w;
  for (; p + 4 < s1; p += 8) {
    int i0 = rte_csr[p];
    int i1 = rte_csr[p + 4];
    unsigned u0 = h4[(size_t)i0 * 64 + lane];
    unsigned u1 = h4[(size_t)i1 * 64 + lane];
    sx += bfLO(u0) + bfLO(u1);
    sy += bfHI(u0) + bfHI(u1);
  }
  for (; p < s1; p += 4) {
    int i0 = rte_csr[p];
    unsigned u0 = h4[(size_t)i0 * 64 + lane];
    sx += bfLO(u0);
    sy += bfHI(u0);
  }
  __shared__ float red[4][HD];
  red[w][lane * 2] = sx;
  red[w][lane * 2 + 1] = sy;
  __syncthreads();
  if (threadIdx.x < HD) {
    int j = threadIdx.x;
    float t = red[0][j] + red[1][j] + red[2][j] + red[3][j];
    partials[((size_t)sp * NR2 + rel) * HD + j] = t;
  }
}

// ---- GRU cell + l2norm for 460 relation rows ----
__global__ __launch_bounds__(HD) void k_gru(
    const float* __restrict__ partials, const float* __restrict__ invcnt,
    const float* __restrict__ emb_rel, const float* __restrict__ h0s,
    const float* __restrict__ Wih, const float* __restrict__ Whh,
    const float* __restrict__ bih, const float* __restrict__ bhh,
    float* __restrict__ h0d) {
  int r = blockIdx.x, j = threadIdx.x;
  __shared__ __align__(16) float xr[2 * HD];
  __shared__ __align__(16) float hh[HD];
  __shared__ float red[HD];
  float inv = invcnt[r];
  xr[j] = emb_rel[r * HD + j];
  float xm = 0.f;
  #pragma unroll
  for (int sp = 0; sp < RSP; ++sp) xm += partials[((size_t)sp * NR2 + r) * HD + j];
  xr[HD + j] = xm * inv;
  float hv0 = h0s[r * HD + j];
  hh[j] = hv0;
  __syncthreads();
  float gr = bih[j], gz = bih[HD + j], gn = bih[2 * HD + j];
  const float4* W4 = (const float4*)Wih;
  int rowA = j * 64, rowB = (j + HD) * 64, rowC = (j + 2 * HD) * 64;
  #pragma unroll 4
  for (int k4 = 0; k4 < 64; ++k4) {
    float4 xa = ((const float4*)xr)[k4];
    float4 w0 = W4[rowA + k4];
    float4 w1 = W4[rowB + k4];
    float4 w2 = W4[rowC + k4];
    gr += w0.x * xa.x + w0.y * xa.y + w0.z * xa.z + w0.w * xa.w;
    gz += w1.x * xa.x + w1.y * xa.y + w1.z * xa.z + w1.w * xa.w;
    gn += w2.x * xa.x + w2.y * xa.y + w2.z * xa.z + w2.w * xa.w;
  }
  float hr = bhh[j], hz = bhh[HD + j], hn = bhh[2 * HD + j];
  const float4* Wh4 = (const float4*)Whh;
  int rA = j * 32, rB = (j + HD) * 32, rC = (j + 2 * HD) * 32;
  #pragma unroll 4
  for (int k4 = 0; k4 < 32; ++k4) {
    float4 xa = ((const float4*)hh)[k4];
    float4 w0 = Wh4[rA + k4];
    float4 w1 = Wh4[rB + k4];
    float4 w2 = Wh4[rC + k4];
    hr += w0.x * xa.x + w0.y * xa.y + w0.z * xa.z + w0.w * xa.w;
    hz += w1.x * xa.x + w1.y * xa.y + w1.z * xa.z + w1.w * xa.w;
    hn += w2.x * xa.x + w2.y * xa.y + w2.z * xa.z + w2.w * xa.w;
  }
  float rg = sigm(gr + hr);
  float zg = sigm(gz + hz);
  float ng = tanhf(gn + rg * hn);
  float hv = (1.0f - zg) * ng + zg * hv0;
  red[j] = hv * hv;
  __syncthreads();
  for (int s = HD / 2; s > 0; s >>= 1) { if (j < s) red[j] += red[j + s]; __syncthreads(); }
  float rn = 1.0f / fmaxf(sqrtf(red[0]), 1e-12f);
  h0d[r * HD + j] = hv * rn;
}

// ---- edge aggregation via dst-CSR (bf16 gathers, packed payload) ----
__global__ __launch_bounds__(256) void k_edge_csr(
    const unsigned short* __restrict__ nh_bf, const float* __restrict__ h0,
    const int* __restrict__ offs, const unsigned* __restrict__ se,
    const float* __restrict__ norm, float* __restrict__ agg) {
  int gw = (blockIdx.x * blockDim.x + threadIdx.x) >> 6;
  int lane = threadIdx.x & 63;
  if (gw >= NENT) return;
  int o0 = offs[gw], o1 = offs[gw + 1];
  const unsigned* nh4 = (const unsigned*)nh_bf;
  const float2* h02 = (const float2*)h0;
  float sx = 0.f, sy = 0.f;
  int p = o0;
  for (; p + 2 <= o1; p += 2) {
    unsigned e0 = se[p];
    unsigned e1 = se[p + 1];
    unsigned ua = nh4[(size_t)(e0 >> 9) * 64 + lane];
    float2 ra = h02[(size_t)(e0 & 511u) * 64 + lane];
    unsigned ub = nh4[(size_t)(e1 >> 9) * 64 + lane];
    float2 rb = h02[(size_t)(e1 & 511u) * 64 + lane];
    sx += (bfLO(ua) + ra.x) + (bfLO(ub) + rb.x);
    sy += (bfHI(ua) + ra.y) + (bfHI(ub) + rb.y);
  }
  if (p < o1) {
    unsigned e0 = se[p];
    unsigned ua = nh4[(size_t)(e0 >> 9) * 64 + lane];
    float2 ra = h02[(size_t)(e0 & 511u) * 64 + lane];
    sx += bfLO(ua) + ra.x;
    sy += bfHI(ua) + ra.y;
  }
  float nm = norm[gw];
  ((float2*)agg)[(size_t)gw * 64 + lane] = make_float2(sx * nm, sy * nm);
}

// ---- MFMA split-bf16: OUT_BF=1 -> write rrelu result as bf16 only; else fp32 in-place ----
template<int OUT_BF>
__global__ __launch_bounds__(256) void k_mm_mfma(
    float* __restrict__ A, unsigned short* __restrict__ Abf,
    const unsigned short* __restrict__ wHi, const unsigned short* __restrict__ wLo,
    int nrows) {
  __shared__ __align__(16) unsigned short AsH[64 * 128];
  __shared__ __align__(16) unsigned short AsL[64 * 128];
  int tid = threadIdx.x;
  int base = blockIdx.x * 64;
  const float4* A4 = (const float4*)A;
  #pragma unroll
  for (int it = 0; it < 8; ++it) {
    int idx = tid + it * 256;          // 0..2047
    int r = idx >> 5, c4 = idx & 31;
    int c0 = c4 * 4;
    float4 v = make_float4(0.f, 0.f, 0.f, 0.f);
    if (base + r < nrows) v = A4[(size_t)(base + r) * 32 + c4];
    int chunk = (c0 >> 3) ^ (r & 7);
    int p = r * 128 + chunk * 8 + (c0 & 7);
    unsigned short h0 = f2bf_rne(v.x), h1 = f2bf_rne(v.y);
    unsigned short h2 = f2bf_rne(v.z), h3 = f2bf_rne(v.w);
    ushort4 hv; hv.x = h0; hv.y = h1; hv.z = h2; hv.w = h3;
    *(ushort4*)&AsH[p] = hv;
    ushort4 lv;
    lv.x = f2bf_rne(v.x - bf2f(h0)); lv.y = f2bf_rne(v.y - bf2f(h1));
    lv.z = f2bf_rne(v.z - bf2f(h2)); lv.w = f2bf_rne(v.w - bf2f(h3));
    *(ushort4*)&AsL[p] = lv;
  }
  __syncthreads();
  int w = tid >> 6, lane = tid & 63;
  int lrow = lane & 15, lk = lane >> 4;
  facc acc[8];
  #pragma unroll
  for (int nt = 0; nt < 8; ++nt) acc[nt] = (facc){0.f, 0.f, 0.f, 0.f};
  int arow = w * 16 + lrow;
  #pragma unroll
  for (int ks = 0; ks < 4; ++ks) {
    int chunk = (ks * 4 + lk) ^ (arow & 7);
    int p = arow * 128 + chunk * 8;
    bfrag aH = *(const bfrag*)&AsH[p];
    bfrag aL = *(const bfrag*)&AsL[p];
    #pragma unroll
    for (int nt = 0; nt < 8; ++nt) {
      int fi = ((nt * 4 + ks) * 64 + lane) * 8;
      bfrag bH = *(const bfrag*)&wHi[fi];
      bfrag bL = *(const bfrag*)&wLo[fi];
      acc[nt] = __builtin_amdgcn_mfma_f32_16x16x32_bf16(aH, bH, acc[nt], 0, 0, 0);
      acc[nt] = __builtin_amdgcn_mfma_f32_16x16x32_bf16(aH, bL, acc[nt], 0, 0, 0);
      acc[nt] = __builtin_amdgcn_mfma_f32_16x16x32_bf16(aL, bH, acc[nt], 0, 0, 0);
    }
  }
  #pragma unroll
  for (int nt = 0; nt < 8; ++nt)
    #pragma unroll
    for (int r = 0; r < 4; ++r) {
      int row = base + w * 16 + lk * 4 + r;
      if (row < nrows) {
        float res = rrelu_f(acc[nt][r]);
        if (OUT_BF) Abf[(size_t)row * HD + nt * 16 + lrow] = f2bf_rne(res);
        else A[(size_t)row * HD + nt * 16 + lrow] = res;
      }
    }
}

// ---- MFMA split-bf16 fused final (+ bf16 shadow of Hout) ----
__global__ __launch_bounds__(256) void k_final_mfma(
    const float* __restrict__ C, const float* __restrict__ Hin, float* __restrict__ Hout,
    unsigned short* __restrict__ Hout_bf,
    const unsigned short* __restrict__ wHi, const unsigned short* __restrict__ wLo,
    const float* __restrict__ bias, int nrows) {
  __shared__ __align__(16) unsigned short AsH[64 * 128];
  __shared__ __align__(16) unsigned short AsL[64 * 128];
  int tid = threadIdx.x;
  int base = blockIdx.x * 64;
  const float4* H4 = (const float4*)Hin;
  #pragma unroll
  for (int it = 0; it < 8; ++it) {
    int idx = tid + it * 256;
    int r = idx >> 5, c4 = idx & 31;
    int c0 = c4 * 4;
    float4 v = make_float4(0.f, 0.f, 0.f, 0.f);
    if (base + r < nrows) v = H4[(size_t)(base + r) * 32 + c4];
    int chunk = (c0 >> 3) ^ (r & 7);
    int p = r * 128 + chunk * 8 + (c0 & 7);
    unsigned short h0 = f2bf_rne(v.x), h1 = f2bf_rne(v.y);
    unsigned short h2 = f2bf_rne(v.z), h3 = f2bf_rne(v.w);
    ushort4 hv; hv.x = h0; hv.y = h1; hv.z = h2; hv.w = h3;
    *(ushort4*)&AsH[p] = hv;
    ushort4 lv;
    lv.x = f2bf_rne(v.x - bf2f(h0)); lv.y = f2bf_rne(v.y - bf2f(h1));
    lv.z = f2bf_rne(v.z - bf2f(h2)); lv.w = f2bf_rne(v.w - bf2f(h3));
    *(ushort4*)&AsL[p] = lv;
  }
  __syncthreads();
  int w = tid >> 6, lane = tid & 63;
  int lrow = lane & 15, lk = lane >> 4;
  facc acc[8];
  #pragma unroll
  for (int nt = 0; nt < 8; ++nt) acc[nt] = (facc){0.f, 0.f, 0.f, 0.f};
  int arow = w * 16 + lrow;
  #pragma unroll
  for (int ks = 0; ks < 4; ++ks) {
    int chunk = (ks * 4 + lk) ^ (arow & 7);
    int p = arow * 128 + chunk * 8;
    bfrag aH = *(const bfrag*)&AsH[p];
    bfrag aL = *(const bfrag*)&AsL[p];
    #pragma unroll
    for (int nt = 0; nt < 8; ++nt) {
      int fi = ((nt * 4 + ks) * 64 + lane) * 8;
      bfrag bH = *(const bfrag*)&wHi[fi];
      bfrag bL = *(const bfrag*)&wLo[fi];
      acc[nt] = __builtin_amdgcn_mfma_f32_16x16x32_bf16(aH, bH, acc[nt], 0, 0, 0);
      acc[nt] = __builtin_amdgcn_mfma_f32_16x16x32_bf16(aH, bL, acc[nt], 0, 0, 0);
      acc[nt] = __builtin_amdgcn_mfma_f32_16x16x32_bf16(aL, bH, acc[nt], 0, 0, 0);
    }
  }
  float cv[8][4];
  float ss[4] = {0.f, 0.f, 0.f, 0.f};
  #pragma unroll
  for (int r = 0; r < 4; ++r) {
    int row = base + w * 16 + lk * 4 + r;
    int rok = row < nrows;
    #pragma unroll
    for (int nt = 0; nt < 8; ++nt) {
      float x = rok ? C[(size_t)row * HD + nt * 16 + lrow] : 0.f;
      cv[nt][r] = x;
      ss[r] += x * x;
    }
  }
  #pragma unroll
  for (int r = 0; r < 4; ++r) {
    #pragma unroll
    for (int o = 1; o < 16; o <<= 1) ss[r] += __shfl_xor(ss[r], o, 64);
    ss[r] = 1.0f / fmaxf(sqrtf(ss[r]), 1e-12f);
  }
  #pragma unroll
  for (int r = 0; r < 4; ++r) {
    int row = base + w * 16 + lk * 4 + r;
    if (row >= nrows) continue;
    #pragma unroll
    for (int nt = 0; nt < 8; ++nt) {
      int col = nt * 16 + lrow;
      float hv = Hin[(size_t)row * HD + col];
      float tw = sigm(acc[nt][r] + bias[col]);
      float res = tw * (cv[nt][r] * ss[r]) + (1.0f - tw) * hv;
      Hout[(size_t)row * HD + col] = res;
      Hout_bf[(size_t)row * HD + col] = f2bf_rne(res);
    }
  }
}

extern "C" void kernel_launch(void* const* d_in, const int* in_sizes, int n_in,
                              void* d_out, int out_size, void* d_ws, size_t ws_size,
                              hipStream_t stream) {
  const int* src    = (const int*)d_in[0];
  const int* dst    = (const int*)d_in[1];
  const int* etype  = (const int*)d_in[2];
  const int* rte    = (const int*)d_in[3];
  const int* rseg   = (const int*)d_in[4];
  const float* dyn  = (const float*)d_in[5];
  const float* emb_rel = (const float*)d_in[6];
  const float* W_ih = (const float*)d_in[7];
  const float* W_hh = (const float*)d_in[8];
  const float* b_ih = (const float*)d_in[9];
  const float* b_hh = (const float*)d_in[10];
  const float* rgcnW = (const float*)d_in[11];
  const float* tgW  = (const float*)d_in[12];
  const float* tgB  = (const float*)d_in[13];
  float* out = (float*)d_out;
  (void)in_sizes; (void)n_in; (void)out_size; (void)ws_size;

  float* ws = (float*)d_ws;
  size_t off = 0;
  float* agg1    = ws + off; off += (size_t)NENT * HD;
  float* agg2    = ws + off; off += (size_t)NENT * HD;
  float* parts   = ws + off; off += (size_t)RSP * NR2 * HD;
  float* h0a     = ws + off; off += (size_t)NR2 * HD;
  float* h0b     = ws + off; off += (size_t)NR2 * HD;
  float* normv8  = ws + off; off += NTOT;
  float* invc8   = ws + off; off += TS * NR2;
  off = (off + 3) & ~(size_t)3;
  unsigned short* h_bf    = (unsigned short*)(ws + off); off += (size_t)NENT * HD / 2;
  unsigned short* agg1_bf = (unsigned short*)(ws + off); off += (size_t)NENT * HD / 2;
  unsigned short* wf = (unsigned short*)(ws + off);
  unsigned short* w1H = wf;            unsigned short* w1L = wf + 16384;
  unsigned short* w2H = wf + 32768;    unsigned short* w2L = wf + 49152;
  unsigned short* wtH = wf + 65536;    unsigned short* wtL = wf + 81920;
  off += (6 * 16384) / 2;
  unsigned* csr_se8 = (unsigned*)(ws + off); off += (size_t)TS * EPC;
  int* csr_rte8  = (int*)(ws + off);  off += (size_t)TS * MPC;
  int* degE8     = (int*)(ws + off);  off += NTOT;
  int* offsE8    = (int*)(ws + off);  off += NTOT + 2;
  int* curE8     = (int*)(ws + off);  off += NTOT;
  int* bsum      = (int*)(ws + off);  off += NB8;
  int* blkcntR8  = (int*)(ws + off);  off += (size_t)TS * RBLK * NR2;
  int* offsR8    = (int*)(ws + off);  off += TS * NR2 + 2;
  int* totR      = (int*)(ws + off);  off += TS * NR2;

  // ===== hoisted, batched CSR builds for all TS steps (input-only) =====
  hipMemsetAsync(degE8, 0, (size_t)NTOT * sizeof(int), stream);
  k_hist<<<2048, 256, 0, stream>>>(dst, degE8, TS * EPC, EPC, NENT);
  k_scan1<<<NB8, 256, 0, stream>>>(degE8, offsE8, normv8, bsum);
  k_scan2<<<1, 256, 0, stream>>>(bsum);
  k_scan3<<<NB8, 256, 0, stream>>>(offsE8, curE8, bsum);
  k_scatterE<<<2048, 256, 0, stream>>>(src, dst, etype, curE8, csr_se8);
  k_histR2<<<dim3(RBLK, TS), 256, 0, stream>>>(rseg, blkcntR8);
  k_scanR2a<<<(TS * NR2 + 255) / 256, 256, 0, stream>>>(blkcntR8, totR);
  k_scanR2b<<<1, 512, 0, stream>>>(totR, offsR8, invc8);
  k_scanR2c<<<(TS * NR2 * 64 + 255) / 256, 256, 0, stream>>>(blkcntR8, offsR8);
  k_scatterR2<<<dim3(RBLK, TS), 256, 0, stream>>>(rte, rseg, blkcntR8, csr_rte8);
  // W fragment prep (bf16 hi/lo)
  k_prepW<<<8, 256, 0, stream>>>(rgcnW, w1H, w1L);
  k_prepW<<<8, 256, 0, stream>>>(rgcnW + HD * HD, w2H, w2L);
  k_prepW<<<8, 256, 0, stream>>>(tgW, wtH, wtL);

  // h_init = l2norm(dynamic_emb) -> d_out slot 0 + bf16 shadow
  k_l2rows<<<NENT, HD, 0, stream>>>(dyn, out, h_bf);

  float* h0bufs[2] = {h0a, h0b};
  for (int t = 0; t < TS; ++t) {
    const float* h = out + (size_t)(t == 0 ? 0 : (t - 1)) * NENT * HD;
    float* hout = out + (size_t)t * NENT * HD;
    const float* h0s = (t == 0) ? emb_rel : h0bufs[(t - 1) & 1];
    float* h0d = h0bufs[t & 1];

    k_relmean<<<dim3(NR2, RSP), 256, 0, stream>>>(h_bf, offsR8 + t * NR2, csr_rte8, parts);
    k_gru<<<NR2, HD, 0, stream>>>(parts, invc8 + t * NR2, emb_rel, h0s,
                                  W_ih, W_hh, b_ih, b_hh, h0d);

    k_edge_csr<<<(NENT * 64 + 255) / 256, 256, 0, stream>>>(
        h_bf, h0d, offsE8 + t * NENT, csr_se8, normv8 + t * NENT, agg1);
    k_mm_mfma<1><<<(NENT + 63) / 64, 256, 0, stream>>>(agg1, agg1_bf, w1H, w1L, NENT);
    k_edge_csr<<<(NENT * 64 + 255) / 256, 256, 0, stream>>>(
        agg1_bf, h0d, offsE8 + t * NENT, csr_se8, normv8 + t * NENT, agg2);
    k_mm_mfma<0><<<(NENT + 63) / 64, 256, 0, stream>>>(agg2, (unsigned short*)nullptr,
                                                       w2H, w2L, NENT);
    // final: writes hout (fp32) and refreshes h_bf for next step (after edge1 consumed it)
    k_final_mfma<<<(NENT + 63) / 64, 256, 0, stream>>>(agg2, h, hout, h_bf,
                                                       wtH, wtL, tgB, NENT);
  }
  hipMemcpyAsync(out + (size_t)TS * NENT * HD, h0bufs[(TS - 1) & 1],
                 (size_t)NR2 * HD * sizeof(float), hipMemcpyDeviceToDevice, stream);
}